// Round 7
// baseline (345.673 us; speedup 1.0000x reference)
//
#include <hip/hip_runtime.h>
#include <math.h>

#define N_NODES 10000
#define N_EDGES 160000
#define ET      (N_EDGES + N_NODES)   // with self loops

typedef unsigned short u16;
typedef __attribute__((ext_vector_type(8))) short bf16x8;
typedef __attribute__((ext_vector_type(4))) float f32x4;

__device__ __forceinline__ u16 f2bf(float f) {            // RNE (weights)
    union { float f; unsigned u; } v; v.f = f;
    unsigned r = (v.u + 0x7FFFu + ((v.u >> 16) & 1u)) >> 16;
    return (u16)r;
}
__device__ __forceinline__ float bf2f(u16 b) {
    union { unsigned u; float f; } v; v.u = ((unsigned)b) << 16;
    return v.f;
}

// in-register split of 8 fp32 (two float4) -> bf16 hi (trunc) + lo (residual)
__device__ __forceinline__ void splitR(const float4& v0, const float4& v1,
                                       bf16x8& hv, bf16x8& lv) {
    float f[8] = {v0.x, v0.y, v0.z, v0.w, v1.x, v1.y, v1.z, v1.w};
    bf16x8 h, l;
#pragma unroll
    for (int i = 0; i < 8; ++i) {
        unsigned u = __float_as_uint(f[i]);
        h[i] = (short)(u >> 16);
        float r = f[i] - __uint_as_float(u & 0xffff0000u);
        l[i] = (short)(__float_as_uint(r) >> 16);
    }
    hv = h; lv = l;
}

#define MFMA3(A_h, A_l, B_h, B_l, ACC)                                            \
    ACC = __builtin_amdgcn_mfma_f32_16x16x32_bf16(A_h, B_h, ACC, 0, 0, 0);        \
    ACC = __builtin_amdgcn_mfma_f32_16x16x32_bf16(A_h, B_l, ACC, 0, 0, 0);        \
    ACC = __builtin_amdgcn_mfma_f32_16x16x32_bf16(A_l, B_h, ACC, 0, 0, 0);

// ---------------------------------------------------------------------------
// all four weights: fp32 [K][N] -> transposed bf16 hi/lo [N][K], one launch
// ---------------------------------------------------------------------------
__global__ void wsplit_all_kernel(const float* __restrict__ W0, u16* o0h, u16* o0l,
                                  const float* __restrict__ W1, u16* o1h, u16* o1l,
                                  const float* __restrict__ W2, u16* o2h, u16* o2l,
                                  const float* __restrict__ W3, u16* o3h, u16* o3l) {
    int idx = blockIdx.x * blockDim.x + threadIdx.x;
    const float* W; u16 *oh, *ol; int N, rel;
    if (idx < 98304)       { W = W0; oh = o0h; ol = o0l; N = 128; rel = idx; }
    else if (idx < 163840) { W = W1; oh = o1h; ol = o1l; N = 512; rel = idx - 98304; }
    else if (idx < 229376) { W = W2; oh = o2h; ol = o2l; N = 128; rel = idx - 163840; }
    else if (idx < 327680) { W = W3; oh = o3h; ol = o3l; N = 768; rel = idx - 229376; }
    else return;
    int K = (N == 128) ? ((idx < 98304) ? 768 : 512) : 128;
    int k = rel / N, n = rel - k * N;
    float v = W[rel];
    u16 h = f2bf(v);
    oh[(size_t)n * K + k] = h;
    ol[(size_t)n * K + k] = f2bf(v - bf2f(h));
}

// ---------------------------------------------------------------------------
// va1[k][h] = sum_c W1[k, h*128+c] * att_src[h][c]  (and att_dst)
// ---------------------------------------------------------------------------
__global__ void va1_kernel(const float* __restrict__ W1,
                           const float* __restrict__ att_src,
                           const float* __restrict__ att_dst,
                           float* __restrict__ vas, float* __restrict__ vad) {
    int tid = threadIdx.x;
    int k = tid >> 2, h = tid & 3;
    float s = 0.0f, d = 0.0f;
    const float* wr = W1 + (size_t)k * 512 + h * 128;
    const float* as = att_src + h * 128;
    const float* ad = att_dst + h * 128;
    for (int c = 0; c < 128; ++c) {
        float w = wr[c];
        s = fmaf(w, as[c], s);
        d = fmaf(w, ad[c], d);
    }
    vas[k * 4 + h] = s;
    vad[k * 4 + h] = d;
}

// ---------------------------------------------------------------------------
// Barrier-free register-pipelined split-bf16 GEMM.
//   C[16 rows x 128 cols per (x,y,z) tile] = A[rows][K] @ B^T + bias
// Block 256 = 4 waves side-by-side in cols; each wave = 16 rows x 32 cols
// (1x2 frags of 16x16). A fp32 loaded straight to registers (coalesced:
// wave reads 16 rows x 128 B-lines per step) and split hi/lo in-reg.
// B bf16 hi/lo direct global (L2-resident). Explicit 2-deep register double
// buffer + full K unroll -> compiler emits counted vmcnt, no syncthreads.
// SRCSEL: z picks A0/A1 and out0/out1 (proj x&g). ZC: col base += z*ZC.
// ---------------------------------------------------------------------------
template<int K, int SRCSEL, int ZC, int ACT, int LDOUT>
__global__ __launch_bounds__(256)
void mmR_kernel(const float* __restrict__ A0, const float* __restrict__ A1,
                size_t azs,
                const u16* __restrict__ Bh, const u16* __restrict__ Bl,
                const float* __restrict__ bias,
                float* __restrict__ out0, float* __restrict__ out1) {
    constexpr int NS = K / 32;
    const int lane = threadIdx.x & 63;
    const int wid  = threadIdx.x >> 6;
    const int lr = lane & 15, q = lane >> 4;
    const int row0 = blockIdx.x * 16;
    const int z = blockIdx.z;
    const int gcb = blockIdx.y * 128 + z * ZC + wid * 32;

    const float* Ab = SRCSEL ? (z ? A1 : A0) : (A0 + (size_t)z * azs);
    float* outp = (SRCSEL && z) ? out1 : out0;

    const int ra = min(row0 + lr, N_NODES - 1);
    const float* pa = Ab + (size_t)ra * K + q * 8;
    const u16* pb0h = Bh + (size_t)(gcb + lr)      * K + q * 8;
    const u16* pb1h = Bh + (size_t)(gcb + 16 + lr) * K + q * 8;
    const u16* pb0l = Bl + (size_t)(gcb + lr)      * K + q * 8;
    const u16* pb1l = Bl + (size_t)(gcb + 16 + lr) * K + q * 8;

    f32x4 acc0 = (f32x4){0.f, 0.f, 0.f, 0.f};
    f32x4 acc1 = (f32x4){0.f, 0.f, 0.f, 0.f};

    float4 aLo[2], aHi[2];
    bf16x8 rb0h[2], rb1h[2], rb0l[2], rb1l[2];

    // prologue: step 0 loads
    aLo[0]  = *(const float4*)(pa);
    aHi[0]  = *(const float4*)(pa + 4);
    rb0h[0] = *(const bf16x8*)(pb0h);
    rb1h[0] = *(const bf16x8*)(pb1h);
    rb0l[0] = *(const bf16x8*)(pb0l);
    rb1l[0] = *(const bf16x8*)(pb1l);

#pragma unroll
    for (int s = 0; s < NS; ++s) {
        const int cur = s & 1, nxt = cur ^ 1;
        if (s + 1 < NS) {
            aLo[nxt]  = *(const float4*)(pa + (s + 1) * 32);
            aHi[nxt]  = *(const float4*)(pa + (s + 1) * 32 + 4);
            rb0h[nxt] = *(const bf16x8*)(pb0h + (s + 1) * 32);
            rb1h[nxt] = *(const bf16x8*)(pb1h + (s + 1) * 32);
            rb0l[nxt] = *(const bf16x8*)(pb0l + (s + 1) * 32);
            rb1l[nxt] = *(const bf16x8*)(pb1l + (s + 1) * 32);
        }
        bf16x8 ah, al;
        splitR(aLo[cur], aHi[cur], ah, al);
        MFMA3(ah, al, rb0h[cur], rb0l[cur], acc0);
        MFMA3(ah, al, rb1h[cur], rb1l[cur], acc1);
    }

    // epilogue: row = row0 + q*4 + i, cols gcb+lr / gcb+16+lr
    int c0 = gcb + lr, c1 = gcb + 16 + lr;
    float bb0 = bias ? bias[c0] : 0.0f;
    float bb1 = bias ? bias[c1] : 0.0f;
#pragma unroll
    for (int i = 0; i < 4; ++i) {
        int orow = row0 + q * 4 + i;
        if (orow < N_NODES) {
            float r0 = acc0[i] + bb0;
            float r1 = acc1[i] + bb1;
            if (ACT == 1) {
                r0 = r0 > 0.0f ? r0 : expm1f(r0);
                r1 = r1 > 0.0f ? r1 : expm1f(r1);
            }
            outp[(size_t)orow * LDOUT + c0] = r0;
            outp[(size_t)orow * LDOUT + c1] = r1;
        }
    }
}

// ---------------------------------------------------------------------------
// gat1 attention logits from xp
// ---------------------------------------------------------------------------
__global__ void att1_kernel(const float* __restrict__ xp,
                            const float* __restrict__ vas,
                            const float* __restrict__ vad,
                            float* __restrict__ as, float* __restrict__ ad) {
    int wv = threadIdx.x >> 6, lane = threadIdx.x & 63;
    int n = blockIdx.x * 4 + wv;
    float2 v = *reinterpret_cast<const float2*>(xp + (size_t)n * 128 + lane * 2);
    float4 s0 = *reinterpret_cast<const float4*>(vas + (lane * 2) * 4);
    float4 s1 = *reinterpret_cast<const float4*>(vas + (lane * 2 + 1) * 4);
    float4 d0 = *reinterpret_cast<const float4*>(vad + (lane * 2) * 4);
    float4 d1 = *reinterpret_cast<const float4*>(vad + (lane * 2 + 1) * 4);
    float ss[4] = { v.x * s0.x + v.y * s1.x, v.x * s0.y + v.y * s1.y,
                    v.x * s0.z + v.y * s1.z, v.x * s0.w + v.y * s1.w };
    float dd[4] = { v.x * d0.x + v.y * d1.x, v.x * d0.y + v.y * d1.y,
                    v.x * d0.z + v.y * d1.z, v.x * d0.w + v.y * d1.w };
#pragma unroll
    for (int m = 32; m > 0; m >>= 1)
#pragma unroll
        for (int h = 0; h < 4; ++h) {
            ss[h] += __shfl_xor(ss[h], m, 64);
            dd[h] += __shfl_xor(dd[h], m, 64);
        }
    if (lane == 0) {
#pragma unroll
        for (int h = 0; h < 4; ++h) {
            as[(size_t)n * 4 + h] = ss[h];
            ad[(size_t)n * 4 + h] = dd[h];
        }
    }
}

// ---------------------------------------------------------------------------
// gat2 attention logits (H=1)
// ---------------------------------------------------------------------------
__global__ void att2_kernel(const float* __restrict__ h,
                            const float* __restrict__ att_src,
                            const float* __restrict__ att_dst,
                            float* __restrict__ as, float* __restrict__ ad) {
    int wv = threadIdx.x >> 6, lane = threadIdx.x & 63;
    int n = blockIdx.x * 4 + wv;
    const float* hp = h + (size_t)n * 128 + lane * 2;
    float2 v = *reinterpret_cast<const float2*>(hp);
    float2 a = *reinterpret_cast<const float2*>(att_src + lane * 2);
    float2 b = *reinterpret_cast<const float2*>(att_dst + lane * 2);
    float ss = v.x * a.x + v.y * a.y;
    float sd = v.x * b.x + v.y * b.y;
#pragma unroll
    for (int m = 32; m > 0; m >>= 1) {
        ss += __shfl_xor(ss, m, 64);
        sd += __shfl_xor(sd, m, 64);
    }
    if (lane == 0) { as[n] = ss; ad[n] = sd; }
}

// ---------------------------------------------------------------------------
// CSR build (by dst)
// ---------------------------------------------------------------------------
__global__ void zero_int_kernel(int* __restrict__ p, int n) {
    int i = blockIdx.x * blockDim.x + threadIdx.x;
    if (i < n) p[i] = 0;
}

__global__ void deg_kernel(const int* __restrict__ ei, int* __restrict__ deg) {
    int e = blockIdx.x * blockDim.x + threadIdx.x;
    if (e >= ET) return;
    int d = (e < N_EDGES) ? ei[N_EDGES + e] : (e - N_EDGES);
    atomicAdd(&deg[d], 1);
}

__global__ void scan_kernel(const int* __restrict__ deg,
                            int* __restrict__ off, int* __restrict__ cur) {
    __shared__ int tmp[1024];
    __shared__ int carry;
    int tid = threadIdx.x;
    if (tid == 0) carry = 0;
    __syncthreads();
    for (int base = 0; base < N_NODES; base += 1024) {
        int i = base + tid;
        int v = (i < N_NODES) ? deg[i] : 0;
        tmp[tid] = v;
        __syncthreads();
        for (int s = 1; s < 1024; s <<= 1) {
            int t = (tid >= s) ? tmp[tid - s] : 0;
            __syncthreads();
            tmp[tid] += t;
            __syncthreads();
        }
        int incl = tmp[tid];
        int ex = carry + incl - v;
        if (i < N_NODES) { off[i] = ex; cur[i] = ex; }
        __syncthreads();
        if (tid == 1023) carry += incl;
        __syncthreads();
    }
    if (tid == 0) off[N_NODES] = carry;
}

__global__ void fill_kernel(const int* __restrict__ ei,
                            int* __restrict__ cur, int* __restrict__ csr_src) {
    int e = blockIdx.x * blockDim.x + threadIdx.x;
    if (e >= ET) return;
    int s, d;
    if (e < N_EDGES) { s = ei[e]; d = ei[N_EDGES + e]; }
    else             { s = e - N_EDGES; d = s; }
    int pos = atomicAdd(&cur[d], 1);
    csr_src[pos] = s;
}

// ---------------------------------------------------------------------------
// Segment softmax, wave-per-node
// ---------------------------------------------------------------------------
template<int H>
__global__ void softmax_kernel(const float* __restrict__ as,
                               const float* __restrict__ ad,
                               const int* __restrict__ off,
                               const int* __restrict__ csr_src,
                               float* __restrict__ exw,     // [ET, H]
                               float* __restrict__ inv_s) { // [N, H]
    int wv = threadIdx.x >> 6, lane = threadIdx.x & 63;
    int n = blockIdx.x * 4 + wv;
    int o0 = off[n], o1 = off[n + 1];
    float adn[H], m[H], s[H];
#pragma unroll
    for (int h = 0; h < H; ++h) { adn[h] = ad[(size_t)n * H + h]; m[h] = -1e30f; s[h] = 0.0f; }

    for (int j = o0 + lane; j < o1; j += 64) {
        int sn = csr_src[j];
#pragma unroll
        for (int h = 0; h < H; ++h) {
            float e = as[(size_t)sn * H + h] + adn[h];
            e = e > 0.0f ? e : 0.2f * e;
            m[h] = fmaxf(m[h], e);
        }
    }
#pragma unroll
    for (int mk = 32; mk > 0; mk >>= 1)
#pragma unroll
        for (int h = 0; h < H; ++h) m[h] = fmaxf(m[h], __shfl_xor(m[h], mk, 64));

    for (int j = o0 + lane; j < o1; j += 64) {
        int sn = csr_src[j];
        float exv[H];
#pragma unroll
        for (int h = 0; h < H; ++h) {
            float e = as[(size_t)sn * H + h] + adn[h];
            e = e > 0.0f ? e : 0.2f * e;
            exv[h] = expf(e - m[h]);
            s[h] += exv[h];
        }
        if (H == 4) {
            *reinterpret_cast<float4*>(exw + (size_t)j * 4) =
                make_float4(exv[0], exv[1], exv[2 % H], exv[3 % H]);
        } else {
            exw[j] = exv[0];
        }
    }
#pragma unroll
    for (int mk = 32; mk > 0; mk >>= 1)
#pragma unroll
        for (int h = 0; h < H; ++h) s[h] += __shfl_xor(s[h], mk, 64);

    if (lane == 0) {
#pragma unroll
        for (int h = 0; h < H; ++h) inv_s[(size_t)n * H + h] = 1.0f / (s[h] + 1e-16f);
    }
}

// ---------------------------------------------------------------------------
// gat1 pre-linear aggregation -> agg fp32 [head][10000][128]
// ---------------------------------------------------------------------------
__global__ void agg1_kernel(const float* __restrict__ xp,
                            const float* __restrict__ exw,
                            const float* __restrict__ inv_s,
                            const int* __restrict__ off,
                            const int* __restrict__ csr_src,
                            float* __restrict__ agg) {
    int n = blockIdx.x;
    int c = threadIdx.x & 127, head = threadIdx.x >> 7;
    int o0 = off[n], o1 = off[n + 1];

    float acc = 0.0f;
    int j = o0;
    for (; j + 4 <= o1; j += 4) {
        int s0 = csr_src[j + 0], s1 = csr_src[j + 1];
        int s2 = csr_src[j + 2], s3 = csr_src[j + 3];
        float w0 = exw[(size_t)(j + 0) * 4 + head];
        float w1 = exw[(size_t)(j + 1) * 4 + head];
        float w2 = exw[(size_t)(j + 2) * 4 + head];
        float w3 = exw[(size_t)(j + 3) * 4 + head];
        float v0 = xp[(size_t)s0 * 128 + c];
        float v1 = xp[(size_t)s1 * 128 + c];
        float v2 = xp[(size_t)s2 * 128 + c];
        float v3 = xp[(size_t)s3 * 128 + c];
        acc = fmaf(w0, v0, acc);
        acc = fmaf(w1, v1, acc);
        acc = fmaf(w2, v2, acc);
        acc = fmaf(w3, v3, acc);
    }
    for (; j < o1; ++j) {
        int sn = csr_src[j];
        acc = fmaf(exw[(size_t)j * 4 + head], xp[(size_t)sn * 128 + c], acc);
    }

    agg[((size_t)head * 10000 + n) * 128 + c] = acc * inv_s[(size_t)n * 4 + head];
}

// ---------------------------------------------------------------------------
// gat2 weighted gather -> hfin fp32 (+bias+beta*gp)
// ---------------------------------------------------------------------------
template<int NPB>
__global__ void gather2_kernel(const float* __restrict__ h,
                               const float* __restrict__ exw,
                               const float* __restrict__ inv_s,
                               const int* __restrict__ off,
                               const int* __restrict__ csr_src,
                               const float* __restrict__ bias,
                               float* __restrict__ outp,
                               const float* __restrict__ gp,
                               const float* __restrict__ beta_p) {
    int sub = threadIdx.x >> 7;
    int c   = threadIdx.x & 127;
    int n   = blockIdx.x * NPB + sub;
    int o0 = off[n], o1 = off[n + 1];

    float acc = 0.0f;
    int j = o0;
    for (; j + 4 <= o1; j += 4) {
        int s0 = csr_src[j + 0], s1 = csr_src[j + 1];
        int s2 = csr_src[j + 2], s3 = csr_src[j + 3];
        float w0 = exw[j + 0], w1 = exw[j + 1];
        float w2 = exw[j + 2], w3 = exw[j + 3];
        float v0 = h[(size_t)s0 * 128 + c];
        float v1 = h[(size_t)s1 * 128 + c];
        float v2 = h[(size_t)s2 * 128 + c];
        float v3 = h[(size_t)s3 * 128 + c];
        acc = fmaf(w0, v0, acc);
        acc = fmaf(w1, v1, acc);
        acc = fmaf(w2, v2, acc);
        acc = fmaf(w3, v3, acc);
    }
    for (; j < o1; ++j) {
        acc = fmaf(exw[j], h[(size_t)csr_src[j] * 128 + c], acc);
    }

    outp[(size_t)n * 128 + c] =
        acc * inv_s[n] + bias[c] + beta_p[0] * gp[(size_t)n * 128 + c];
}

// ---------------------------------------------------------------------------
extern "C" void kernel_launch(void* const* d_in, const int* in_sizes, int n_in,
                              void* d_out, int out_size, void* d_ws, size_t ws_size,
                              hipStream_t stream) {
    const float* x      = (const float*)d_in[0];
    const int*   ei     = (const int*)  d_in[1];
    const float* g      = (const float*)d_in[2];
    const float* proj_W = (const float*)d_in[3];
    const float* proj_b = (const float*)d_in[4];
    const float* gat1_W = (const float*)d_in[5];
    const float* g1_as  = (const float*)d_in[6];
    const float* g1_ad  = (const float*)d_in[7];
    const float* gat1_b = (const float*)d_in[8];
    const float* gat2_W = (const float*)d_in[9];
    const float* g2_as  = (const float*)d_in[10];
    const float* g2_ad  = (const float*)d_in[11];
    const float* gat2_b = (const float*)d_in[12];
    const float* dec_W  = (const float*)d_in[13];
    const float* dec_b  = (const float*)d_in[14];
    const float* beta   = (const float*)d_in[15];
    float* out = (float*)d_out;

    // ---- workspace carve (regions reused in stream order) ----
    char* p = (char*)d_ws;
    auto alloc = [&](size_t b) { void* r = (void*)p; p += (b + 255) & ~(size_t)255; return r; };
    float* helu = (float*)alloc((size_t)10000 * 512 * 4);      // 20.5 MB
    float* agg  = (float*)alloc((size_t)4 * 10000 * 128 * 4);  // 20.5 MB; hfin alias
    float* xp   = (float*)alloc((size_t)10000 * 128 * 4);      // h2 alias
    float* gp   = (float*)alloc((size_t)10000 * 128 * 4);
    u16*   pwh  = (u16*)alloc(768 * 128 * 2);
    u16*   pwl  = (u16*)alloc(768 * 128 * 2);
    u16*   w1h  = (u16*)alloc(128 * 512 * 2);
    u16*   w1l  = (u16*)alloc(128 * 512 * 2);
    u16*   w2h  = (u16*)alloc(512 * 128 * 2);
    u16*   w2l  = (u16*)alloc(512 * 128 * 2);
    u16*   wdh  = (u16*)alloc(128 * 768 * 2);
    u16*   wdl  = (u16*)alloc(128 * 768 * 2);
    float* va1s = (float*)alloc(128 * 4 * 4);
    float* va1d = (float*)alloc(128 * 4 * 4);
    float* a1s  = (float*)alloc((size_t)N_NODES * 4 * 4);
    float* a1d  = (float*)alloc((size_t)N_NODES * 4 * 4);
    float* a2s  = (float*)alloc((size_t)N_NODES * 4);
    float* a2d  = (float*)alloc((size_t)N_NODES * 4);
    float* is1  = (float*)alloc((size_t)N_NODES * 4 * 4);
    float* is2  = (float*)alloc((size_t)N_NODES * 4);
    float* exw4 = (float*)alloc((size_t)ET * 4 * 4);
    float* exw1 = (float*)alloc((size_t)ET * 4);
    int*   deg  = (int*)alloc((size_t)N_NODES * 4);
    int*   off  = (int*)alloc((size_t)(N_NODES + 1) * 4);
    int*   cur  = (int*)alloc((size_t)N_NODES * 4);
    int*   csr  = (int*)alloc((size_t)ET * 4);
    // aliases (stream-ordered reuse)
    float* h2   = xp;    // after att1/agg1 done with xp
    float* hfin = agg;   // after mm_head done with agg

    const int GR = (N_NODES + 15) / 16;   // 625 row-blocks

    // ---- weight prep + CSR ----
    hipLaunchKernelGGL(wsplit_all_kernel, dim3(1280), dim3(256), 0, stream,
                       proj_W, pwh, pwl, gat1_W, w1h, w1l,
                       gat2_W, w2h, w2l, dec_W, wdh, wdl);
    hipLaunchKernelGGL(va1_kernel, dim3(1), dim3(512), 0, stream,
                       gat1_W, g1_as, g1_ad, va1s, va1d);
    hipLaunchKernelGGL(zero_int_kernel, dim3((N_NODES + 255) / 256), dim3(256), 0, stream, deg, N_NODES);
    hipLaunchKernelGGL(deg_kernel, dim3((ET + 255) / 256), dim3(256), 0, stream, ei, deg);
    hipLaunchKernelGGL(scan_kernel, dim3(1), dim3(1024), 0, stream, deg, off, cur);
    hipLaunchKernelGGL(fill_kernel, dim3((ET + 255) / 256), dim3(256), 0, stream, ei, cur, csr);

    // ---- proj: xp = x@Wp+b, gp = g@Wp+b (z selects src) ----
    hipLaunchKernelGGL((mmR_kernel<768, 1, 0, 0, 128>), dim3(GR, 1, 2), dim3(256), 0, stream,
                       x, g, (size_t)0, pwh, pwl, proj_b, xp, gp);

    // ---- gat1: logits from xp (h1 never materialized) ----
    hipLaunchKernelGGL(att1_kernel, dim3(N_NODES / 4), dim3(256), 0, stream,
                       xp, va1s, va1d, a1s, a1d);
    hipLaunchKernelGGL(softmax_kernel<4>, dim3(N_NODES / 4), dim3(256), 0, stream,
                       a1s, a1d, off, csr, exw4, is1);
    hipLaunchKernelGGL(agg1_kernel, dim3(N_NODES), dim3(512), 0, stream,
                       xp, exw4, is1, off, csr, agg);
    // per-head linear + bias + elu: helu[n, z*128+c]
    hipLaunchKernelGGL((mmR_kernel<128, 0, 128, 1, 512>), dim3(GR, 1, 4), dim3(256), 0, stream,
                       agg, (const float*)nullptr, (size_t)10000 * 128,
                       w1h, w1l, gat1_b, helu, (float*)nullptr);

    // ---- gat2 linear: h2 = helu @ W2 (full K=512) ----
    hipLaunchKernelGGL((mmR_kernel<512, 0, 0, 0, 128>), dim3(GR, 1, 1), dim3(256), 0, stream,
                       helu, (const float*)nullptr, (size_t)0,
                       w2h, w2l, (const float*)nullptr, h2, (float*)nullptr);
    hipLaunchKernelGGL(att2_kernel, dim3(N_NODES / 4), dim3(256), 0, stream,
                       h2, g2_as, g2_ad, a2s, a2d);
    hipLaunchKernelGGL(softmax_kernel<1>, dim3(N_NODES / 4), dim3(256), 0, stream,
                       a2s, a2d, off, csr, exw1, is2);
    hipLaunchKernelGGL((gather2_kernel<2>), dim3(N_NODES / 2), dim3(256), 0, stream,
                       h2, exw1, is2, off, csr, gat2_b, hfin, gp, beta);

    // ---- decoder: out = hfin @ Wd + b ----
    hipLaunchKernelGGL((mmR_kernel<128, 0, 0, 0, 768>), dim3(GR, 6, 1), dim3(256), 0, stream,
                       hfin, (const float*)nullptr, (size_t)0,
                       wdh, wdl, dec_b, out, (float*)nullptr);
}

// Round 8
// 220.309 us; speedup vs baseline: 1.5690x; 1.5690x over previous
//
#include <hip/hip_runtime.h>
#include <math.h>

#define N_NODES 10000
#define N_EDGES 160000
#define ET      (N_EDGES + N_NODES)   // with self loops

typedef unsigned short u16;
typedef __attribute__((ext_vector_type(8))) short bf16x8;
typedef __attribute__((ext_vector_type(4))) float f32x4;

__device__ __forceinline__ u16 f2bf(float f) {            // RNE (weights)
    union { float f; unsigned u; } v; v.f = f;
    unsigned r = (v.u + 0x7FFFu + ((v.u >> 16) & 1u)) >> 16;
    return (u16)r;
}
__device__ __forceinline__ float bf2f(u16 b) {
    union { unsigned u; float f; } v; v.u = ((unsigned)b) << 16;
    return v.f;
}

// in-register A split: 8 consecutive fp32 -> bf16 hi (trunc) + lo (exact resid)
__device__ __forceinline__ void splitA8(const float* __restrict__ p,
                                        bf16x8& hv, bf16x8& lv) {
    float4 v0 = *reinterpret_cast<const float4*>(p);
    float4 v1 = *reinterpret_cast<const float4*>(p + 4);
    float f[8] = {v0.x, v0.y, v0.z, v0.w, v1.x, v1.y, v1.z, v1.w};
    bf16x8 h, l;
#pragma unroll
    for (int i = 0; i < 8; ++i) {
        unsigned u = __float_as_uint(f[i]);
        h[i] = (short)(u >> 16);
        float r = f[i] - __uint_as_float(u & 0xffff0000u);
        l[i] = (short)(__float_as_uint(r) >> 16);
    }
    hv = h; lv = l;
}

#define MFMA3(A_h, A_l, B_h, B_l, ACC)                                            \
    ACC = __builtin_amdgcn_mfma_f32_16x16x32_bf16(A_h, B_h, ACC, 0, 0, 0);        \
    ACC = __builtin_amdgcn_mfma_f32_16x16x32_bf16(A_h, B_l, ACC, 0, 0, 0);        \
    ACC = __builtin_amdgcn_mfma_f32_16x16x32_bf16(A_l, B_h, ACC, 0, 0, 0);

// async global->LDS, 16 B per lane, wave-uniform LDS base
#define GLD16(SRC, DST)                                                           \
    __builtin_amdgcn_global_load_lds(                                             \
        (const __attribute__((address_space(1))) void*)(SRC),                     \
        (__attribute__((address_space(3))) void*)(DST), 16, 0, 0)

// ---------------------------------------------------------------------------
// Weight pack: fp32 W[K][N] -> MFMA-fragment-ordered bf16 hi/lo.
// Chunk rel = (cg, kb, fn, lane), lane fastest. Chunk holds 8 u16:
//   col = cg*32 + fn*16 + (lane&15),  k = kb*32 + (lane>>4)*8 + j
// Output offset = rel*8 u16 -> a wave's fragment load is base + lane*16B
// (fully coalesced 1KB), replacing 64-line scattered per-lane B reads.
// ---------------------------------------------------------------------------
__global__ void wpack_all_kernel(const float* __restrict__ W0, u16* p0h, u16* p0l,
                                 const float* __restrict__ W1, u16* p1h, u16* p1l,
                                 const float* __restrict__ W2, u16* p2h, u16* p2l,
                                 const float* __restrict__ W3, u16* p3h, u16* p3l) {
    int idx = blockIdx.x * blockDim.x + threadIdx.x;
    const float* W; u16 *oh, *ol; int K, N, rel;
    if      (idx < 12288) { W = W0; oh = p0h; ol = p0l; K = 768; N = 128; rel = idx; }
    else if (idx < 20480) { W = W1; oh = p1h; ol = p1l; K = 128; N = 512; rel = idx - 12288; }
    else if (idx < 28672) { W = W2; oh = p2h; ol = p2l; K = 512; N = 128; rel = idx - 20480; }
    else if (idx < 40960) { W = W3; oh = p3h; ol = p3l; K = 128; N = 768; rel = idx - 28672; }
    else return;
    int perCg = (K / 32) * 128;
    int cg = rel / perCg, r2 = rel - cg * perCg;
    int kb = r2 >> 7, r3 = r2 & 127;
    int fn = r3 >> 6, lane = r3 & 63;
    int col = cg * 32 + fn * 16 + (lane & 15);
    int k0  = kb * 32 + (lane >> 4) * 8;
    bf16x8 hv, lv;
#pragma unroll
    for (int j = 0; j < 8; ++j) {
        float v = W[(size_t)(k0 + j) * N + col];
        u16 h = f2bf(v);
        hv[j] = (short)h;
        lv[j] = (short)f2bf(v - bf2f(h));
    }
    *(bf16x8*)(oh + (size_t)rel * 8) = hv;
    *(bf16x8*)(ol + (size_t)rel * 8) = lv;
}

// ---------------------------------------------------------------------------
// va1[k][h] = sum_c W1[k, h*128+c] * att_src[h][c]  (and att_dst)
// ---------------------------------------------------------------------------
__global__ void va1_kernel(const float* __restrict__ W1,
                           const float* __restrict__ att_src,
                           const float* __restrict__ att_dst,
                           float* __restrict__ vas, float* __restrict__ vad) {
    int tid = threadIdx.x;
    int k = tid >> 2, h = tid & 3;
    float s = 0.0f, d = 0.0f;
    const float* wr = W1 + (size_t)k * 512 + h * 128;
    const float* as = att_src + h * 128;
    const float* ad = att_dst + h * 128;
    for (int c = 0; c < 128; ++c) {
        float w = wr[c];
        s = fmaf(w, as[c], s);
        d = fmaf(w, ad[c], d);
    }
    vas[k * 4 + h] = s;
    vad[k * 4 + h] = d;
}

// ---------------------------------------------------------------------------
// Unified LDS-pipelined split-bf16 GEMM (round-6 structure, packed-B loads).
//   C[rows 10000, 128 cols per (y,z) tile] = A[rows][K] @ B^T + bias
// Block 256 thr = 4 waves side-by-side (each 32 rows x 32 cols = 2x2 frags).
// A fp32 staged async into LDS (double-buffered, BK=64), split in-reg.
// B bf16 hi/lo in fragment-packed layout -> coalesced register loads,
// register double-buffered.
// SRCSEL: z picks A0/A1 and out0/out1 (proj x&g). ZC: col base += z*ZC (heads).
// ---------------------------------------------------------------------------
template<int K, int SRCSEL, int ZC, int ACT, int LDOUT>
__global__ __launch_bounds__(256)
void mmT_kernel(const float* __restrict__ A0, const float* __restrict__ A1,
                size_t azs,
                const u16* __restrict__ Bh, const u16* __restrict__ Bl,
                const float* __restrict__ bias,
                float* __restrict__ out0, float* __restrict__ out1) {
    constexpr int NS = K / 64;
    __shared__ float smem[2 * 2080];           // 2 buffers x 8*260 floats
    const int lane = threadIdx.x & 63;
    const int wid  = threadIdx.x >> 6;
    const int lr = lane & 15, q = lane >> 4;
    const int row0 = blockIdx.x * 32;
    const int z = blockIdx.z;
    const int gcb = blockIdx.y * 128 + z * ZC;

    const float* Ab = SRCSEL ? (z ? A1 : A0) : (A0 + (size_t)z * azs);
    float* outp = (SRCSEL && z) ? out1 : out0;

    // staging: wave wid owns ku groups wid*2, wid*2+1; lane l -> row l>>1, half l&1
    const int srow = min(row0 + (lane >> 1), N_NODES - 1);
    const float* sA = Ab + (size_t)srow * K + (lane & 1) * 4;
    float* dg0 = smem + (wid * 2 + 0) * 260;
    float* dg1 = smem + (wid * 2 + 1) * 260;

    // packed B: wave's col-group cg; fragment (kb, fn) at chunk (kb*2+fn)*512 u16
    const int cg = gcb / 32 + wid;
    const u16* pbh = Bh + (size_t)cg * K * 32 + lane * 8;
    const u16* pbl = Bl + (size_t)cg * K * 32 + lane * 8;

    f32x4 acc[2][2];
#pragma unroll
    for (int i = 0; i < 2; ++i)
#pragma unroll
        for (int j = 0; j < 2; ++j) acc[i][j] = (f32x4){0.f, 0.f, 0.f, 0.f};

    bf16x8 rbh[2][2][2], rbl[2][2][2];         // [bank][fn][ksub]

#define STAGE_T(BUF, S) do {                                                   \
        GLD16(sA + (S) * 64 + (wid * 2 + 0) * 8, dg0 + (BUF) * 2080);          \
        GLD16(sA + (S) * 64 + (wid * 2 + 1) * 8, dg1 + (BUF) * 2080);          \
    } while (0)

    // prologue: tile 0
    STAGE_T(0, 0);
#pragma unroll
    for (int fn = 0; fn < 2; ++fn)
#pragma unroll
        for (int ks = 0; ks < 2; ++ks) {
            rbh[0][fn][ks] = *(const bf16x8*)(pbh + (ks * 2 + fn) * 512);
            rbl[0][fn][ks] = *(const bf16x8*)(pbl + (ks * 2 + fn) * 512);
        }
    __syncthreads();

#pragma unroll
    for (int s = 0; s < NS; ++s) {
        const int bank = s & 1;
        if (s + 1 < NS) {
            STAGE_T(bank ^ 1, s + 1);
#pragma unroll
            for (int fn = 0; fn < 2; ++fn)
#pragma unroll
                for (int ks = 0; ks < 2; ++ks) {
                    rbh[bank ^ 1][fn][ks] =
                        *(const bf16x8*)(pbh + (((s + 1) * 2 + ks) * 2 + fn) * 512);
                    rbl[bank ^ 1][fn][ks] =
                        *(const bf16x8*)(pbl + (((s + 1) * 2 + ks) * 2 + fn) * 512);
                }
        }
        const float* lb = smem + bank * 2080;
        bf16x8 ah[2][2], al[2][2];             // [fm][ksub]
#pragma unroll
        for (int fm = 0; fm < 2; ++fm)
#pragma unroll
            for (int ks = 0; ks < 2; ++ks) {
                const float* fp = lb + (ks * 4 + q) * 260 + (fm * 16 + lr) * 8;
                splitA8(fp, ah[fm][ks], al[fm][ks]);
            }
#pragma unroll
        for (int fm = 0; fm < 2; ++fm)
#pragma unroll
            for (int fn = 0; fn < 2; ++fn)
#pragma unroll
                for (int ks = 0; ks < 2; ++ks) {
                    MFMA3(ah[fm][ks], al[fm][ks],
                          rbh[bank][fn][ks], rbl[bank][fn][ks], acc[fm][fn]);
                }
        __syncthreads();
    }

    int orq = q * 4;
#pragma unroll
    for (int fm = 0; fm < 2; ++fm)
#pragma unroll
        for (int fn = 0; fn < 2; ++fn) {
            int col = gcb + wid * 32 + fn * 16 + lr;
            float bb = bias ? bias[col] : 0.0f;
#pragma unroll
            for (int i = 0; i < 4; ++i) {
                int orow = row0 + fm * 16 + orq + i;
                if (orow < N_NODES) {
                    float r = acc[fm][fn][i] + bb;
                    if (ACT == 1) r = r > 0.0f ? r : expm1f(r);
                    outp[(size_t)orow * LDOUT + col] = r;
                }
            }
        }
#undef STAGE_T
}

// ---------------------------------------------------------------------------
// gat1 attention logits from xp
// ---------------------------------------------------------------------------
__global__ void att1_kernel(const float* __restrict__ xp,
                            const float* __restrict__ vas,
                            const float* __restrict__ vad,
                            float* __restrict__ as, float* __restrict__ ad) {
    int wv = threadIdx.x >> 6, lane = threadIdx.x & 63;
    int n = blockIdx.x * 4 + wv;
    float2 v = *reinterpret_cast<const float2*>(xp + (size_t)n * 128 + lane * 2);
    float4 s0 = *reinterpret_cast<const float4*>(vas + (lane * 2) * 4);
    float4 s1 = *reinterpret_cast<const float4*>(vas + (lane * 2 + 1) * 4);
    float4 d0 = *reinterpret_cast<const float4*>(vad + (lane * 2) * 4);
    float4 d1 = *reinterpret_cast<const float4*>(vad + (lane * 2 + 1) * 4);
    float ss[4] = { v.x * s0.x + v.y * s1.x, v.x * s0.y + v.y * s1.y,
                    v.x * s0.z + v.y * s1.z, v.x * s0.w + v.y * s1.w };
    float dd[4] = { v.x * d0.x + v.y * d1.x, v.x * d0.y + v.y * d1.y,
                    v.x * d0.z + v.y * d1.z, v.x * d0.w + v.y * d1.w };
#pragma unroll
    for (int m = 32; m > 0; m >>= 1)
#pragma unroll
        for (int h = 0; h < 4; ++h) {
            ss[h] += __shfl_xor(ss[h], m, 64);
            dd[h] += __shfl_xor(dd[h], m, 64);
        }
    if (lane == 0) {
#pragma unroll
        for (int h = 0; h < 4; ++h) {
            as[(size_t)n * 4 + h] = ss[h];
            ad[(size_t)n * 4 + h] = dd[h];
        }
    }
}

// ---------------------------------------------------------------------------
// gat2 attention logits (H=1)
// ---------------------------------------------------------------------------
__global__ void att2_kernel(const float* __restrict__ h,
                            const float* __restrict__ att_src,
                            const float* __restrict__ att_dst,
                            float* __restrict__ as, float* __restrict__ ad) {
    int wv = threadIdx.x >> 6, lane = threadIdx.x & 63;
    int n = blockIdx.x * 4 + wv;
    const float* hp = h + (size_t)n * 128 + lane * 2;
    float2 v = *reinterpret_cast<const float2*>(hp);
    float2 a = *reinterpret_cast<const float2*>(att_src + lane * 2);
    float2 b = *reinterpret_cast<const float2*>(att_dst + lane * 2);
    float ss = v.x * a.x + v.y * a.y;
    float sd = v.x * b.x + v.y * b.y;
#pragma unroll
    for (int m = 32; m > 0; m >>= 1) {
        ss += __shfl_xor(ss, m, 64);
        sd += __shfl_xor(sd, m, 64);
    }
    if (lane == 0) { as[n] = ss; ad[n] = sd; }
}

// ---------------------------------------------------------------------------
// CSR build (by dst)
// ---------------------------------------------------------------------------
__global__ void zero_int_kernel(int* __restrict__ p, int n) {
    int i = blockIdx.x * blockDim.x + threadIdx.x;
    if (i < n) p[i] = 0;
}

__global__ void deg_kernel(const int* __restrict__ ei, int* __restrict__ deg) {
    int e = blockIdx.x * blockDim.x + threadIdx.x;
    if (e >= ET) return;
    int d = (e < N_EDGES) ? ei[N_EDGES + e] : (e - N_EDGES);
    atomicAdd(&deg[d], 1);
}

__global__ void scan_kernel(const int* __restrict__ deg,
                            int* __restrict__ off, int* __restrict__ cur) {
    __shared__ int tmp[1024];
    __shared__ int carry;
    int tid = threadIdx.x;
    if (tid == 0) carry = 0;
    __syncthreads();
    for (int base = 0; base < N_NODES; base += 1024) {
        int i = base + tid;
        int v = (i < N_NODES) ? deg[i] : 0;
        tmp[tid] = v;
        __syncthreads();
        for (int s = 1; s < 1024; s <<= 1) {
            int t = (tid >= s) ? tmp[tid - s] : 0;
            __syncthreads();
            tmp[tid] += t;
            __syncthreads();
        }
        int incl = tmp[tid];
        int ex = carry + incl - v;
        if (i < N_NODES) { off[i] = ex; cur[i] = ex; }
        __syncthreads();
        if (tid == 1023) carry += incl;
        __syncthreads();
    }
    if (tid == 0) off[N_NODES] = carry;
}

__global__ void fill_kernel(const int* __restrict__ ei,
                            int* __restrict__ cur, int* __restrict__ csr_src) {
    int e = blockIdx.x * blockDim.x + threadIdx.x;
    if (e >= ET) return;
    int s, d;
    if (e < N_EDGES) { s = ei[e]; d = ei[N_EDGES + e]; }
    else             { s = e - N_EDGES; d = s; }
    int pos = atomicAdd(&cur[d], 1);
    csr_src[pos] = s;
}

// ---------------------------------------------------------------------------
// Segment softmax, wave-per-node
// ---------------------------------------------------------------------------
template<int H>
__global__ void softmax_kernel(const float* __restrict__ as,
                               const float* __restrict__ ad,
                               const int* __restrict__ off,
                               const int* __restrict__ csr_src,
                               float* __restrict__ exw,     // [ET, H]
                               float* __restrict__ inv_s) { // [N, H]
    int wv = threadIdx.x >> 6, lane = threadIdx.x & 63;
    int n = blockIdx.x * 4 + wv;
    int o0 = off[n], o1 = off[n + 1];
    float adn[H], m[H], s[H];
#pragma unroll
    for (int h = 0; h < H; ++h) { adn[h] = ad[(size_t)n * H + h]; m[h] = -1e30f; s[h] = 0.0f; }

    for (int j = o0 + lane; j < o1; j += 64) {
        int sn = csr_src[j];
#pragma unroll
        for (int h = 0; h < H; ++h) {
            float e = as[(size_t)sn * H + h] + adn[h];
            e = e > 0.0f ? e : 0.2f * e;
            m[h] = fmaxf(m[h], e);
        }
    }
#pragma unroll
    for (int mk = 32; mk > 0; mk >>= 1)
#pragma unroll
        for (int h = 0; h < H; ++h) m[h] = fmaxf(m[h], __shfl_xor(m[h], mk, 64));

    for (int j = o0 + lane; j < o1; j += 64) {
        int sn = csr_src[j];
        float exv[H];
#pragma unroll
        for (int h = 0; h < H; ++h) {
            float e = as[(size_t)sn * H + h] + adn[h];
            e = e > 0.0f ? e : 0.2f * e;
            exv[h] = expf(e - m[h]);
            s[h] += exv[h];
        }
        if (H == 4) {
            *reinterpret_cast<float4*>(exw + (size_t)j * 4) =
                make_float4(exv[0], exv[1], exv[2 % H], exv[3 % H]);
        } else {
            exw[j] = exv[0];
        }
    }
#pragma unroll
    for (int mk = 32; mk > 0; mk >>= 1)
#pragma unroll
        for (int h = 0; h < H; ++h) s[h] += __shfl_xor(s[h], mk, 64);

    if (lane == 0) {
#pragma unroll
        for (int h = 0; h < H; ++h) inv_s[(size_t)n * H + h] = 1.0f / (s[h] + 1e-16f);
    }
}

// ---------------------------------------------------------------------------
// gat1 pre-linear aggregation -> agg fp32 [head][10000][128]
// ---------------------------------------------------------------------------
__global__ void agg1_kernel(const float* __restrict__ xp,
                            const float* __restrict__ exw,
                            const float* __restrict__ inv_s,
                            const int* __restrict__ off,
                            const int* __restrict__ csr_src,
                            float* __restrict__ agg) {
    int n = blockIdx.x;
    int c = threadIdx.x & 127, head = threadIdx.x >> 7;
    int o0 = off[n], o1 = off[n + 1];

    float acc = 0.0f;
    int j = o0;
    for (; j + 4 <= o1; j += 4) {
        int s0 = csr_src[j + 0], s1 = csr_src[j + 1];
        int s2 = csr_src[j + 2], s3 = csr_src[j + 3];
        float w0 = exw[(size_t)(j + 0) * 4 + head];
        float w1 = exw[(size_t)(j + 1) * 4 + head];
        float w2 = exw[(size_t)(j + 2) * 4 + head];
        float w3 = exw[(size_t)(j + 3) * 4 + head];
        float v0 = xp[(size_t)s0 * 128 + c];
        float v1 = xp[(size_t)s1 * 128 + c];
        float v2 = xp[(size_t)s2 * 128 + c];
        float v3 = xp[(size_t)s3 * 128 + c];
        acc = fmaf(w0, v0, acc);
        acc = fmaf(w1, v1, acc);
        acc = fmaf(w2, v2, acc);
        acc = fmaf(w3, v3, acc);
    }
    for (; j < o1; ++j) {
        int sn = csr_src[j];
        acc = fmaf(exw[(size_t)j * 4 + head], xp[(size_t)sn * 128 + c], acc);
    }

    agg[((size_t)head * 10000 + n) * 128 + c] = acc * inv_s[(size_t)n * 4 + head];
}

// ---------------------------------------------------------------------------
// gat2 weighted gather -> hfin fp32 (+bias+beta*gp)
// ---------------------------------------------------------------------------
template<int NPB>
__global__ void gather2_kernel(const float* __restrict__ h,
                               const float* __restrict__ exw,
                               const float* __restrict__ inv_s,
                               const int* __restrict__ off,
                               const int* __restrict__ csr_src,
                               const float* __restrict__ bias,
                               float* __restrict__ outp,
                               const float* __restrict__ gp,
                               const float* __restrict__ beta_p) {
    int sub = threadIdx.x >> 7;
    int c   = threadIdx.x & 127;
    int n   = blockIdx.x * NPB + sub;
    int o0 = off[n], o1 = off[n + 1];

    float acc = 0.0f;
    int j = o0;
    for (; j + 4 <= o1; j += 4) {
        int s0 = csr_src[j + 0], s1 = csr_src[j + 1];
        int s2 = csr_src[j + 2], s3 = csr_src[j + 3];
        float w0 = exw[j + 0], w1 = exw[j + 1];
        float w2 = exw[j + 2], w3 = exw[j + 3];
        float v0 = h[(size_t)s0 * 128 + c];
        float v1 = h[(size_t)s1 * 128 + c];
        float v2 = h[(size_t)s2 * 128 + c];
        float v3 = h[(size_t)s3 * 128 + c];
        acc = fmaf(w0, v0, acc);
        acc = fmaf(w1, v1, acc);
        acc = fmaf(w2, v2, acc);
        acc = fmaf(w3, v3, acc);
    }
    for (; j < o1; ++j) {
        acc = fmaf(exw[j], h[(size_t)csr_src[j] * 128 + c], acc);
    }

    outp[(size_t)n * 128 + c] =
        acc * inv_s[n] + bias[c] + beta_p[0] * gp[(size_t)n * 128 + c];
}

// ---------------------------------------------------------------------------
extern "C" void kernel_launch(void* const* d_in, const int* in_sizes, int n_in,
                              void* d_out, int out_size, void* d_ws, size_t ws_size,
                              hipStream_t stream) {
    const float* x      = (const float*)d_in[0];
    const int*   ei     = (const int*)  d_in[1];
    const float* g      = (const float*)d_in[2];
    const float* proj_W = (const float*)d_in[3];
    const float* proj_b = (const float*)d_in[4];
    const float* gat1_W = (const float*)d_in[5];
    const float* g1_as  = (const float*)d_in[6];
    const float* g1_ad  = (const float*)d_in[7];
    const float* gat1_b = (const float*)d_in[8];
    const float* gat2_W = (const float*)d_in[9];
    const float* g2_as  = (const float*)d_in[10];
    const float* g2_ad  = (const float*)d_in[11];
    const float* gat2_b = (const float*)d_in[12];
    const float* dec_W  = (const float*)d_in[13];
    const float* dec_b  = (const float*)d_in[14];
    const float* beta   = (const float*)d_in[15];
    float* out = (float*)d_out;

    // ---- workspace carve (regions reused in stream order) ----
    char* p = (char*)d_ws;
    auto alloc = [&](size_t b) { void* r = (void*)p; p += (b + 255) & ~(size_t)255; return r; };
    float* helu = (float*)alloc((size_t)10000 * 512 * 4);      // 20.5 MB
    float* agg  = (float*)alloc((size_t)4 * 10000 * 128 * 4);  // 20.5 MB; hfin alias
    float* xp   = (float*)alloc((size_t)10000 * 128 * 4);      // h2 alias
    float* gp   = (float*)alloc((size_t)10000 * 128 * 4);
    u16*   pwh  = (u16*)alloc(768 * 128 * 2);
    u16*   pwl  = (u16*)alloc(768 * 128 * 2);
    u16*   w1h  = (u16*)alloc(128 * 512 * 2);
    u16*   w1l  = (u16*)alloc(128 * 512 * 2);
    u16*   w2h  = (u16*)alloc(512 * 128 * 2);
    u16*   w2l  = (u16*)alloc(512 * 128 * 2);
    u16*   wdh  = (u16*)alloc(128 * 768 * 2);
    u16*   wdl  = (u16*)alloc(128 * 768 * 2);
    float* va1s = (float*)alloc(128 * 4 * 4);
    float* va1d = (float*)alloc(128 * 4 * 4);
    float* a1s  = (float*)alloc((size_t)N_NODES * 4 * 4);
    float* a1d  = (float*)alloc((size_t)N_NODES * 4 * 4);
    float* a2s  = (float*)alloc((size_t)N_NODES * 4);
    float* a2d  = (float*)alloc((size_t)N_NODES * 4);
    float* is1  = (float*)alloc((size_t)N_NODES * 4 * 4);
    float* is2  = (float*)alloc((size_t)N_NODES * 4);
    float* exw4 = (float*)alloc((size_t)ET * 4 * 4);
    float* exw1 = (float*)alloc((size_t)ET * 4);
    int*   deg  = (int*)alloc((size_t)N_NODES * 4);
    int*   off  = (int*)alloc((size_t)(N_NODES + 1) * 4);
    int*   cur  = (int*)alloc((size_t)N_NODES * 4);
    int*   csr  = (int*)alloc((size_t)ET * 4);
    // aliases (stream-ordered reuse)
    float* h2   = xp;    // after att1/agg1 done with xp
    float* hfin = agg;   // after mm_head done with agg

    const int GR = (N_NODES + 31) / 32;   // 313 row-blocks

    // ---- weight prep + CSR ----
    hipLaunchKernelGGL(wpack_all_kernel, dim3(160), dim3(256), 0, stream,
                       proj_W, pwh, pwl, gat1_W, w1h, w1l,
                       gat2_W, w2h, w2l, dec_W, wdh, wdl);
    hipLaunchKernelGGL(va1_kernel, dim3(1), dim3(512), 0, stream,
                       gat1_W, g1_as, g1_ad, va1s, va1d);
    hipLaunchKernelGGL(zero_int_kernel, dim3((N_NODES + 255) / 256), dim3(256), 0, stream, deg, N_NODES);
    hipLaunchKernelGGL(deg_kernel, dim3((ET + 255) / 256), dim3(256), 0, stream, ei, deg);
    hipLaunchKernelGGL(scan_kernel, dim3(1), dim3(1024), 0, stream, deg, off, cur);
    hipLaunchKernelGGL(fill_kernel, dim3((ET + 255) / 256), dim3(256), 0, stream, ei, cur, csr);

    // ---- proj: xp = x@Wp+b, gp = g@Wp+b (z selects src; full K) ----
    hipLaunchKernelGGL((mmT_kernel<768, 1, 0, 0, 128>), dim3(GR, 1, 2), dim3(256), 0, stream,
                       x, g, (size_t)0, pwh, pwl, proj_b, xp, gp);

    // ---- gat1: logits from xp (h1 never materialized) ----
    hipLaunchKernelGGL(att1_kernel, dim3(N_NODES / 4), dim3(256), 0, stream,
                       xp, va1s, va1d, a1s, a1d);
    hipLaunchKernelGGL(softmax_kernel<4>, dim3(N_NODES / 4), dim3(256), 0, stream,
                       a1s, a1d, off, csr, exw4, is1);
    hipLaunchKernelGGL(agg1_kernel, dim3(N_NODES), dim3(512), 0, stream,
                       xp, exw4, is1, off, csr, agg);
    // per-head linear + bias + elu: helu[n, z*128+c]
    hipLaunchKernelGGL((mmT_kernel<128, 0, 128, 1, 512>), dim3(GR, 1, 4), dim3(256), 0, stream,
                       agg, (const float*)nullptr, (size_t)10000 * 128,
                       w1h, w1l, gat1_b, helu, (float*)nullptr);

    // ---- gat2 linear: h2 = helu @ W2 (full K=512) ----
    hipLaunchKernelGGL((mmT_kernel<512, 0, 0, 0, 128>), dim3(GR, 1, 1), dim3(256), 0, stream,
                       helu, (const float*)nullptr, (size_t)0,
                       w2h, w2l, (const float*)nullptr, h2, (float*)nullptr);
    hipLaunchKernelGGL(att2_kernel, dim3(N_NODES / 4), dim3(256), 0, stream,
                       h2, g2_as, g2_ad, a2s, a2d);
    hipLaunchKernelGGL(softmax_kernel<1>, dim3(N_NODES / 4), dim3(256), 0, stream,
                       a2s, a2d, off, csr, exw1, is2);
    hipLaunchKernelGGL((gather2_kernel<2>), dim3(N_NODES / 2), dim3(256), 0, stream,
                       h2, exw1, is2, off, csr, gat2_b, hfin, gp, beta);

    // ---- decoder: out = hfin @ Wd + b ----
    hipLaunchKernelGGL((mmT_kernel<128, 0, 0, 0, 768>), dim3(GR, 6, 1), dim3(256), 0, stream,
                       hfin, (const float*)nullptr, (size_t)0,
                       wdh, wdl, dec_b, out, (float*)nullptr);
}

// Round 9
// 211.204 us; speedup vs baseline: 1.6367x; 1.0431x over previous
//
#include <hip/hip_runtime.h>
#include <math.h>

#define N_NODES 10000
#define N_EDGES 160000
#define ET      (N_EDGES + N_NODES)   // with self loops

typedef unsigned short u16;
typedef __attribute__((ext_vector_type(8))) short bf16x8;
typedef __attribute__((ext_vector_type(4))) float f32x4;

__device__ __forceinline__ u16 f2bf(float f) {            // RNE (weights)
    union { float f; unsigned u; } v; v.f = f;
    unsigned r = (v.u + 0x7FFFu + ((v.u >> 16) & 1u)) >> 16;
    return (u16)r;
}
__device__ __forceinline__ float bf2f(u16 b) {
    union { unsigned u; float f; } v; v.u = ((unsigned)b) << 16;
    return v.f;
}

// in-register A split: 8 consecutive fp32 -> bf16 hi (trunc) + lo (exact resid)
__device__ __forceinline__ void splitA8(const float* __restrict__ p,
                                        bf16x8& hv, bf16x8& lv) {
    float4 v0 = *reinterpret_cast<const float4*>(p);
    float4 v1 = *reinterpret_cast<const float4*>(p + 4);
    float f[8] = {v0.x, v0.y, v0.z, v0.w, v1.x, v1.y, v1.z, v1.w};
    bf16x8 h, l;
#pragma unroll
    for (int i = 0; i < 8; ++i) {
        unsigned u = __float_as_uint(f[i]);
        h[i] = (short)(u >> 16);
        float r = f[i] - __uint_as_float(u & 0xffff0000u);
        l[i] = (short)(__float_as_uint(r) >> 16);
    }
    hv = h; lv = l;
}

#define MFMA3(A_h, A_l, B_h, B_l, ACC)                                            \
    ACC = __builtin_amdgcn_mfma_f32_16x16x32_bf16(A_h, B_h, ACC, 0, 0, 0);        \
    ACC = __builtin_amdgcn_mfma_f32_16x16x32_bf16(A_h, B_l, ACC, 0, 0, 0);        \
    ACC = __builtin_amdgcn_mfma_f32_16x16x32_bf16(A_l, B_h, ACC, 0, 0, 0);

// async global->LDS, 16 B per lane, wave-uniform LDS base
#define GLD16(SRC, DST)                                                           \
    __builtin_amdgcn_global_load_lds(                                             \
        (const __attribute__((address_space(1))) void*)(SRC),                     \
        (__attribute__((address_space(3))) void*)(DST), 16, 0, 0)

// ---------------------------------------------------------------------------
// Weight pack: fp32 W[K][N] -> MFMA-fragment-ordered bf16 hi/lo.
// Chunk rel = (cg, kb, fn, lane), lane fastest. Chunk holds 8 u16:
//   col = cg*32 + fn*16 + (lane&15),  k = kb*32 + (lane>>4)*8 + j
// ---------------------------------------------------------------------------
__global__ void wpack_all_kernel(const float* __restrict__ W0, u16* p0h, u16* p0l,
                                 const float* __restrict__ W1, u16* p1h, u16* p1l,
                                 const float* __restrict__ W2, u16* p2h, u16* p2l,
                                 const float* __restrict__ W3, u16* p3h, u16* p3l) {
    int idx = blockIdx.x * blockDim.x + threadIdx.x;
    const float* W; u16 *oh, *ol; int K, N, rel;
    if      (idx < 12288) { W = W0; oh = p0h; ol = p0l; K = 768; N = 128; rel = idx; }
    else if (idx < 20480) { W = W1; oh = p1h; ol = p1l; K = 128; N = 512; rel = idx - 12288; }
    else if (idx < 28672) { W = W2; oh = p2h; ol = p2l; K = 512; N = 128; rel = idx - 20480; }
    else if (idx < 40960) { W = W3; oh = p3h; ol = p3l; K = 128; N = 768; rel = idx - 28672; }
    else return;
    int perCg = (K / 32) * 128;
    int cg = rel / perCg, r2 = rel - cg * perCg;
    int kb = r2 >> 7, r3 = r2 & 127;
    int fn = r3 >> 6, lane = r3 & 63;
    int col = cg * 32 + fn * 16 + (lane & 15);
    int k0  = kb * 32 + (lane >> 4) * 8;
    bf16x8 hv, lv;
#pragma unroll
    for (int j = 0; j < 8; ++j) {
        float v = W[(size_t)(k0 + j) * N + col];
        u16 h = f2bf(v);
        hv[j] = (short)h;
        lv[j] = (short)f2bf(v - bf2f(h));
    }
    *(bf16x8*)(oh + (size_t)rel * 8) = hv;
    *(bf16x8*)(ol + (size_t)rel * 8) = lv;
}

// ---------------------------------------------------------------------------
// va1[k][h] = sum_c W1[k, h*128+c] * att_src[h][c]  (and att_dst)
// ---------------------------------------------------------------------------
__global__ void va1_kernel(const float* __restrict__ W1,
                           const float* __restrict__ att_src,
                           const float* __restrict__ att_dst,
                           float* __restrict__ vas, float* __restrict__ vad) {
    int tid = threadIdx.x;
    int k = tid >> 2, h = tid & 3;
    float s = 0.0f, d = 0.0f;
    const float* wr = W1 + (size_t)k * 512 + h * 128;
    const float* as = att_src + h * 128;
    const float* ad = att_dst + h * 128;
    for (int c = 0; c < 128; ++c) {
        float w = wr[c];
        s = fmaf(w, as[c], s);
        d = fmaf(w, ad[c], d);
    }
    vas[k * 4 + h] = s;
    vad[k * 4 + h] = d;
}

// ---------------------------------------------------------------------------
// Unified LDS-pipelined split-bf16 GEMM (packed-B loads).
// ---------------------------------------------------------------------------
template<int K, int SRCSEL, int ZC, int ACT, int LDOUT>
__global__ __launch_bounds__(256)
void mmT_kernel(const float* __restrict__ A0, const float* __restrict__ A1,
                size_t azs,
                const u16* __restrict__ Bh, const u16* __restrict__ Bl,
                const float* __restrict__ bias,
                float* __restrict__ out0, float* __restrict__ out1) {
    constexpr int NS = K / 64;
    __shared__ float smem[2 * 2080];           // 2 buffers x 8*260 floats
    const int lane = threadIdx.x & 63;
    const int wid  = threadIdx.x >> 6;
    const int lr = lane & 15, q = lane >> 4;
    const int row0 = blockIdx.x * 32;
    const int z = blockIdx.z;
    const int gcb = blockIdx.y * 128 + z * ZC;

    const float* Ab = SRCSEL ? (z ? A1 : A0) : (A0 + (size_t)z * azs);
    float* outp = (SRCSEL && z) ? out1 : out0;

    // staging: wave wid owns ku groups wid*2, wid*2+1; lane l -> row l>>1, half l&1
    const int srow = min(row0 + (lane >> 1), N_NODES - 1);
    const float* sA = Ab + (size_t)srow * K + (lane & 1) * 4;
    float* dg0 = smem + (wid * 2 + 0) * 260;
    float* dg1 = smem + (wid * 2 + 1) * 260;

    // packed B: wave's col-group cg; fragment (kb, fn) at chunk (kb*2+fn)*512 u16
    const int cg = gcb / 32 + wid;
    const u16* pbh = Bh + (size_t)cg * K * 32 + lane * 8;
    const u16* pbl = Bl + (size_t)cg * K * 32 + lane * 8;

    f32x4 acc[2][2];
#pragma unroll
    for (int i = 0; i < 2; ++i)
#pragma unroll
        for (int j = 0; j < 2; ++j) acc[i][j] = (f32x4){0.f, 0.f, 0.f, 0.f};

    bf16x8 rbh[2][2][2], rbl[2][2][2];         // [bank][fn][ksub]

#define STAGE_T(BUF, S) do {                                                   \
        GLD16(sA + (S) * 64 + (wid * 2 + 0) * 8, dg0 + (BUF) * 2080);          \
        GLD16(sA + (S) * 64 + (wid * 2 + 1) * 8, dg1 + (BUF) * 2080);          \
    } while (0)

    // prologue: tile 0
    STAGE_T(0, 0);
#pragma unroll
    for (int fn = 0; fn < 2; ++fn)
#pragma unroll
        for (int ks = 0; ks < 2; ++ks) {
            rbh[0][fn][ks] = *(const bf16x8*)(pbh + (ks * 2 + fn) * 512);
            rbl[0][fn][ks] = *(const bf16x8*)(pbl + (ks * 2 + fn) * 512);
        }
    __syncthreads();

#pragma unroll
    for (int s = 0; s < NS; ++s) {
        const int bank = s & 1;
        if (s + 1 < NS) {
            STAGE_T(bank ^ 1, s + 1);
#pragma unroll
            for (int fn = 0; fn < 2; ++fn)
#pragma unroll
                for (int ks = 0; ks < 2; ++ks) {
                    rbh[bank ^ 1][fn][ks] =
                        *(const bf16x8*)(pbh + (((s + 1) * 2 + ks) * 2 + fn) * 512);
                    rbl[bank ^ 1][fn][ks] =
                        *(const bf16x8*)(pbl + (((s + 1) * 2 + ks) * 2 + fn) * 512);
                }
        }
        const float* lb = smem + bank * 2080;
        bf16x8 ah[2][2], al[2][2];             // [fm][ksub]
#pragma unroll
        for (int fm = 0; fm < 2; ++fm)
#pragma unroll
            for (int ks = 0; ks < 2; ++ks) {
                const float* fp = lb + (ks * 4 + q) * 260 + (fm * 16 + lr) * 8;
                splitA8(fp, ah[fm][ks], al[fm][ks]);
            }
#pragma unroll
        for (int fm = 0; fm < 2; ++fm)
#pragma unroll
            for (int fn = 0; fn < 2; ++fn)
#pragma unroll
                for (int ks = 0; ks < 2; ++ks) {
                    MFMA3(ah[fm][ks], al[fm][ks],
                          rbh[bank][fn][ks], rbl[bank][fn][ks], acc[fm][fn]);
                }
        __syncthreads();
    }

    int orq = q * 4;
#pragma unroll
    for (int fm = 0; fm < 2; ++fm)
#pragma unroll
        for (int fn = 0; fn < 2; ++fn) {
            int col = gcb + wid * 32 + fn * 16 + lr;
            float bb = bias ? bias[col] : 0.0f;
#pragma unroll
            for (int i = 0; i < 4; ++i) {
                int orow = row0 + fm * 16 + orq + i;
                if (orow < N_NODES) {
                    float r = acc[fm][fn][i] + bb;
                    if (ACT == 1) r = r > 0.0f ? r : expm1f(r);
                    outp[(size_t)orow * LDOUT + col] = r;
                }
            }
        }
#undef STAGE_T
}

// ---------------------------------------------------------------------------
// gat1 attention logits from xp
// ---------------------------------------------------------------------------
__global__ void att1_kernel(const float* __restrict__ xp,
                            const float* __restrict__ vas,
                            const float* __restrict__ vad,
                            float* __restrict__ as, float* __restrict__ ad) {
    int wv = threadIdx.x >> 6, lane = threadIdx.x & 63;
    int n = blockIdx.x * 4 + wv;
    float2 v = *reinterpret_cast<const float2*>(xp + (size_t)n * 128 + lane * 2);
    float4 s0 = *reinterpret_cast<const float4*>(vas + (lane * 2) * 4);
    float4 s1 = *reinterpret_cast<const float4*>(vas + (lane * 2 + 1) * 4);
    float4 d0 = *reinterpret_cast<const float4*>(vad + (lane * 2) * 4);
    float4 d1 = *reinterpret_cast<const float4*>(vad + (lane * 2 + 1) * 4);
    float ss[4] = { v.x * s0.x + v.y * s1.x, v.x * s0.y + v.y * s1.y,
                    v.x * s0.z + v.y * s1.z, v.x * s0.w + v.y * s1.w };
    float dd[4] = { v.x * d0.x + v.y * d1.x, v.x * d0.y + v.y * d1.y,
                    v.x * d0.z + v.y * d1.z, v.x * d0.w + v.y * d1.w };
#pragma unroll
    for (int m = 32; m > 0; m >>= 1)
#pragma unroll
        for (int h = 0; h < 4; ++h) {
            ss[h] += __shfl_xor(ss[h], m, 64);
            dd[h] += __shfl_xor(dd[h], m, 64);
        }
    if (lane == 0) {
#pragma unroll
        for (int h = 0; h < 4; ++h) {
            as[(size_t)n * 4 + h] = ss[h];
            ad[(size_t)n * 4 + h] = dd[h];
        }
    }
}

// ---------------------------------------------------------------------------
// gat2 attention logits (H=1)
// ---------------------------------------------------------------------------
__global__ void att2_kernel(const float* __restrict__ h,
                            const float* __restrict__ att_src,
                            const float* __restrict__ att_dst,
                            float* __restrict__ as, float* __restrict__ ad) {
    int wv = threadIdx.x >> 6, lane = threadIdx.x & 63;
    int n = blockIdx.x * 4 + wv;
    const float* hp = h + (size_t)n * 128 + lane * 2;
    float2 v = *reinterpret_cast<const float2*>(hp);
    float2 a = *reinterpret_cast<const float2*>(att_src + lane * 2);
    float2 b = *reinterpret_cast<const float2*>(att_dst + lane * 2);
    float ss = v.x * a.x + v.y * a.y;
    float sd = v.x * b.x + v.y * b.y;
#pragma unroll
    for (int m = 32; m > 0; m >>= 1) {
        ss += __shfl_xor(ss, m, 64);
        sd += __shfl_xor(sd, m, 64);
    }
    if (lane == 0) { as[n] = ss; ad[n] = sd; }
}

// ---------------------------------------------------------------------------
// CSR build (by dst)
// ---------------------------------------------------------------------------
__global__ void zero_int_kernel(int* __restrict__ p, int n) {
    int i = blockIdx.x * blockDim.x + threadIdx.x;
    if (i < n) p[i] = 0;
}

__global__ void deg_kernel(const int* __restrict__ ei, int* __restrict__ deg) {
    int e = blockIdx.x * blockDim.x + threadIdx.x;
    if (e >= ET) return;
    int d = (e < N_EDGES) ? ei[N_EDGES + e] : (e - N_EDGES);
    atomicAdd(&deg[d], 1);
}

__global__ void scan_kernel(const int* __restrict__ deg,
                            int* __restrict__ off, int* __restrict__ cur) {
    __shared__ int tmp[1024];
    __shared__ int carry;
    int tid = threadIdx.x;
    if (tid == 0) carry = 0;
    __syncthreads();
    for (int base = 0; base < N_NODES; base += 1024) {
        int i = base + tid;
        int v = (i < N_NODES) ? deg[i] : 0;
        tmp[tid] = v;
        __syncthreads();
        for (int s = 1; s < 1024; s <<= 1) {
            int t = (tid >= s) ? tmp[tid - s] : 0;
            __syncthreads();
            tmp[tid] += t;
            __syncthreads();
        }
        int incl = tmp[tid];
        int ex = carry + incl - v;
        if (i < N_NODES) { off[i] = ex; cur[i] = ex; }
        __syncthreads();
        if (tid == 1023) carry += incl;
        __syncthreads();
    }
    if (tid == 0) off[N_NODES] = carry;
}

__global__ void fill_kernel(const int* __restrict__ ei,
                            int* __restrict__ cur, int* __restrict__ csr_src) {
    int e = blockIdx.x * blockDim.x + threadIdx.x;
    if (e >= ET) return;
    int s, d;
    if (e < N_EDGES) { s = ei[e]; d = ei[N_EDGES + e]; }
    else             { s = e - N_EDGES; d = s; }
    int pos = atomicAdd(&cur[d], 1);
    csr_src[pos] = s;
}

// ---------------------------------------------------------------------------
// Segment softmax, wave-per-node
// ---------------------------------------------------------------------------
template<int H>
__global__ void softmax_kernel(const float* __restrict__ as,
                               const float* __restrict__ ad,
                               const int* __restrict__ off,
                               const int* __restrict__ csr_src,
                               float* __restrict__ exw,     // [ET, H]
                               float* __restrict__ inv_s) { // [N, H]
    int wv = threadIdx.x >> 6, lane = threadIdx.x & 63;
    int n = blockIdx.x * 4 + wv;
    int o0 = off[n], o1 = off[n + 1];
    float adn[H], m[H], s[H];
#pragma unroll
    for (int h = 0; h < H; ++h) { adn[h] = ad[(size_t)n * H + h]; m[h] = -1e30f; s[h] = 0.0f; }

    for (int j = o0 + lane; j < o1; j += 64) {
        int sn = csr_src[j];
#pragma unroll
        for (int h = 0; h < H; ++h) {
            float e = as[(size_t)sn * H + h] + adn[h];
            e = e > 0.0f ? e : 0.2f * e;
            m[h] = fmaxf(m[h], e);
        }
    }
#pragma unroll
    for (int mk = 32; mk > 0; mk >>= 1)
#pragma unroll
        for (int h = 0; h < H; ++h) m[h] = fmaxf(m[h], __shfl_xor(m[h], mk, 64));

    for (int j = o0 + lane; j < o1; j += 64) {
        int sn = csr_src[j];
        float exv[H];
#pragma unroll
        for (int h = 0; h < H; ++h) {
            float e = as[(size_t)sn * H + h] + adn[h];
            e = e > 0.0f ? e : 0.2f * e;
            exv[h] = expf(e - m[h]);
            s[h] += exv[h];
        }
        if (H == 4) {
            *reinterpret_cast<float4*>(exw + (size_t)j * 4) =
                make_float4(exv[0], exv[1], exv[2 % H], exv[3 % H]);
        } else {
            exw[j] = exv[0];
        }
    }
#pragma unroll
    for (int mk = 32; mk > 0; mk >>= 1)
#pragma unroll
        for (int h = 0; h < H; ++h) s[h] += __shfl_xor(s[h], mk, 64);

    if (lane == 0) {
#pragma unroll
        for (int h = 0; h < H; ++h) inv_s[(size_t)n * H + h] = 1.0f / (s[h] + 1e-16f);
    }
}

// ---------------------------------------------------------------------------
// gat1 pre-linear aggregation -> agg fp32 [head][10000][128]
// One thread per channel accumulates ALL 4 heads: 1 xp load + 1 float4
// weight load (wave-uniform broadcast) per edge, vs 4x redundant before.
// Block 256 = 2 nodes x 128 channels.
// ---------------------------------------------------------------------------
__global__ void agg1_kernel(const float* __restrict__ xp,
                            const float* __restrict__ exw,    // [ET][4]
                            const float* __restrict__ inv_s,  // [N][4]
                            const int* __restrict__ off,
                            const int* __restrict__ csr_src,
                            float* __restrict__ agg) {
    int sub = threadIdx.x >> 7;
    int c   = threadIdx.x & 127;
    int n   = blockIdx.x * 2 + sub;
    int o0 = off[n], o1 = off[n + 1];

    float a0 = 0.f, a1 = 0.f, a2 = 0.f, a3 = 0.f;
    int j = o0;
    for (; j + 2 <= o1; j += 2) {
        int s0 = csr_src[j], s1 = csr_src[j + 1];
        float4 w0 = *reinterpret_cast<const float4*>(exw + (size_t)j * 4);
        float4 w1 = *reinterpret_cast<const float4*>(exw + (size_t)(j + 1) * 4);
        float v0 = xp[(size_t)s0 * 128 + c];
        float v1 = xp[(size_t)s1 * 128 + c];
        a0 = fmaf(w0.x, v0, a0); a1 = fmaf(w0.y, v0, a1);
        a2 = fmaf(w0.z, v0, a2); a3 = fmaf(w0.w, v0, a3);
        a0 = fmaf(w1.x, v1, a0); a1 = fmaf(w1.y, v1, a1);
        a2 = fmaf(w1.z, v1, a2); a3 = fmaf(w1.w, v1, a3);
    }
    if (j < o1) {
        int s0 = csr_src[j];
        float4 w0 = *reinterpret_cast<const float4*>(exw + (size_t)j * 4);
        float v0 = xp[(size_t)s0 * 128 + c];
        a0 = fmaf(w0.x, v0, a0); a1 = fmaf(w0.y, v0, a1);
        a2 = fmaf(w0.z, v0, a2); a3 = fmaf(w0.w, v0, a3);
    }

    float4 inv = *reinterpret_cast<const float4*>(inv_s + (size_t)n * 4);
    agg[((size_t)0 * 10000 + n) * 128 + c] = a0 * inv.x;
    agg[((size_t)1 * 10000 + n) * 128 + c] = a1 * inv.y;
    agg[((size_t)2 * 10000 + n) * 128 + c] = a2 * inv.z;
    agg[((size_t)3 * 10000 + n) * 128 + c] = a3 * inv.w;
}

// ---------------------------------------------------------------------------
// gat2 weighted gather -> hfin fp32 (+bias+beta*gp)
// ---------------------------------------------------------------------------
template<int NPB>
__global__ void gather2_kernel(const float* __restrict__ h,
                               const float* __restrict__ exw,
                               const float* __restrict__ inv_s,
                               const int* __restrict__ off,
                               const int* __restrict__ csr_src,
                               const float* __restrict__ bias,
                               float* __restrict__ outp,
                               const float* __restrict__ gp,
                               const float* __restrict__ beta_p) {
    int sub = threadIdx.x >> 7;
    int c   = threadIdx.x & 127;
    int n   = blockIdx.x * NPB + sub;
    int o0 = off[n], o1 = off[n + 1];

    float acc = 0.0f;
    int j = o0;
    for (; j + 4 <= o1; j += 4) {
        int s0 = csr_src[j + 0], s1 = csr_src[j + 1];
        int s2 = csr_src[j + 2], s3 = csr_src[j + 3];
        float w0 = exw[j + 0], w1 = exw[j + 1];
        float w2 = exw[j + 2], w3 = exw[j + 3];
        float v0 = h[(size_t)s0 * 128 + c];
        float v1 = h[(size_t)s1 * 128 + c];
        float v2 = h[(size_t)s2 * 128 + c];
        float v3 = h[(size_t)s3 * 128 + c];
        acc = fmaf(w0, v0, acc);
        acc = fmaf(w1, v1, acc);
        acc = fmaf(w2, v2, acc);
        acc = fmaf(w3, v3, acc);
    }
    for (; j < o1; ++j) {
        acc = fmaf(exw[j], h[(size_t)csr_src[j] * 128 + c], acc);
    }

    outp[(size_t)n * 128 + c] =
        acc * inv_s[n] + bias[c] + beta_p[0] * gp[(size_t)n * 128 + c];
}

// ---------------------------------------------------------------------------
extern "C" void kernel_launch(void* const* d_in, const int* in_sizes, int n_in,
                              void* d_out, int out_size, void* d_ws, size_t ws_size,
                              hipStream_t stream) {
    const float* x      = (const float*)d_in[0];
    const int*   ei     = (const int*)  d_in[1];
    const float* g      = (const float*)d_in[2];
    const float* proj_W = (const float*)d_in[3];
    const float* proj_b = (const float*)d_in[4];
    const float* gat1_W = (const float*)d_in[5];
    const float* g1_as  = (const float*)d_in[6];
    const float* g1_ad  = (const float*)d_in[7];
    const float* gat1_b = (const float*)d_in[8];
    const float* gat2_W = (const float*)d_in[9];
    const float* g2_as  = (const float*)d_in[10];
    const float* g2_ad  = (const float*)d_in[11];
    const float* gat2_b = (const float*)d_in[12];
    const float* dec_W  = (const float*)d_in[13];
    const float* dec_b  = (const float*)d_in[14];
    const float* beta   = (const float*)d_in[15];
    float* out = (float*)d_out;

    // ---- workspace carve (regions reused in stream order) ----
    char* p = (char*)d_ws;
    auto alloc = [&](size_t b) { void* r = (void*)p; p += (b + 255) & ~(size_t)255; return r; };
    float* helu = (float*)alloc((size_t)10000 * 512 * 4);      // 20.5 MB
    float* agg  = (float*)alloc((size_t)4 * 10000 * 128 * 4);  // 20.5 MB; hfin alias
    float* xp   = (float*)alloc((size_t)10000 * 128 * 4);      // h2 alias
    float* gp   = (float*)alloc((size_t)10000 * 128 * 4);
    u16*   pwh  = (u16*)alloc(768 * 128 * 2);
    u16*   pwl  = (u16*)alloc(768 * 128 * 2);
    u16*   w1h  = (u16*)alloc(128 * 512 * 2);
    u16*   w1l  = (u16*)alloc(128 * 512 * 2);
    u16*   w2h  = (u16*)alloc(512 * 128 * 2);
    u16*   w2l  = (u16*)alloc(512 * 128 * 2);
    u16*   wdh  = (u16*)alloc(128 * 768 * 2);
    u16*   wdl  = (u16*)alloc(128 * 768 * 2);
    float* va1s = (float*)alloc(128 * 4 * 4);
    float* va1d = (float*)alloc(128 * 4 * 4);
    float* a1s  = (float*)alloc((size_t)N_NODES * 4 * 4);
    float* a1d  = (float*)alloc((size_t)N_NODES * 4 * 4);
    float* a2s  = (float*)alloc((size_t)N_NODES * 4);
    float* a2d  = (float*)alloc((size_t)N_NODES * 4);
    float* is1  = (float*)alloc((size_t)N_NODES * 4 * 4);
    float* is2  = (float*)alloc((size_t)N_NODES * 4);
    float* exw4 = (float*)alloc((size_t)ET * 4 * 4);
    float* exw1 = (float*)alloc((size_t)ET * 4);
    int*   deg  = (int*)alloc((size_t)N_NODES * 4);
    int*   off  = (int*)alloc((size_t)(N_NODES + 1) * 4);
    int*   cur  = (int*)alloc((size_t)N_NODES * 4);
    int*   csr  = (int*)alloc((size_t)ET * 4);
    // aliases (stream-ordered reuse)
    float* h2   = xp;    // after att1/agg1 done with xp
    float* hfin = agg;   // after mm_head done with agg

    const int GR = (N_NODES + 31) / 32;   // 313 row-blocks

    // ---- weight prep + CSR ----
    hipLaunchKernelGGL(wpack_all_kernel, dim3(160), dim3(256), 0, stream,
                       proj_W, pwh, pwl, gat1_W, w1h, w1l,
                       gat2_W, w2h, w2l, dec_W, wdh, wdl);
    hipLaunchKernelGGL(va1_kernel, dim3(1), dim3(512), 0, stream,
                       gat1_W, g1_as, g1_ad, va1s, va1d);
    hipLaunchKernelGGL(zero_int_kernel, dim3((N_NODES + 255) / 256), dim3(256), 0, stream, deg, N_NODES);
    hipLaunchKernelGGL(deg_kernel, dim3((ET + 255) / 256), dim3(256), 0, stream, ei, deg);
    hipLaunchKernelGGL(scan_kernel, dim3(1), dim3(1024), 0, stream, deg, off, cur);
    hipLaunchKernelGGL(fill_kernel, dim3((ET + 255) / 256), dim3(256), 0, stream, ei, cur, csr);

    // ---- proj: xp = x@Wp+b, gp = g@Wp+b (z selects src; full K) ----
    hipLaunchKernelGGL((mmT_kernel<768, 1, 0, 0, 128>), dim3(GR, 1, 2), dim3(256), 0, stream,
                       x, g, (size_t)0, pwh, pwl, proj_b, xp, gp);

    // ---- gat1: logits from xp (h1 never materialized) ----
    hipLaunchKernelGGL(att1_kernel, dim3(N_NODES / 4), dim3(256), 0, stream,
                       xp, va1s, va1d, a1s, a1d);
    hipLaunchKernelGGL(softmax_kernel<4>, dim3(N_NODES / 4), dim3(256), 0, stream,
                       a1s, a1d, off, csr, exw4, is1);
    hipLaunchKernelGGL(agg1_kernel, dim3(N_NODES / 2), dim3(256), 0, stream,
                       xp, exw4, is1, off, csr, agg);
    // per-head linear + bias + elu: helu[n, z*128+c]
    hipLaunchKernelGGL((mmT_kernel<128, 0, 128, 1, 512>), dim3(GR, 1, 4), dim3(256), 0, stream,
                       agg, (const float*)nullptr, (size_t)10000 * 128,
                       w1h, w1l, gat1_b, helu, (float*)nullptr);

    // ---- gat2 linear: h2 = helu @ W2 (full K=512) ----
    hipLaunchKernelGGL((mmT_kernel<512, 0, 0, 0, 128>), dim3(GR, 1, 1), dim3(256), 0, stream,
                       helu, (const float*)nullptr, (size_t)0,
                       w2h, w2l, (const float*)nullptr, h2, (float*)nullptr);
    hipLaunchKernelGGL(att2_kernel, dim3(N_NODES / 4), dim3(256), 0, stream,
                       h2, g2_as, g2_ad, a2s, a2d);
    hipLaunchKernelGGL(softmax_kernel<1>, dim3(N_NODES / 4), dim3(256), 0, stream,
                       a2s, a2d, off, csr, exw1, is2);
    hipLaunchKernelGGL((gather2_kernel<2>), dim3(N_NODES / 2), dim3(256), 0, stream,
                       h2, exw1, is2, off, csr, gat2_b, hfin, gp, beta);

    // ---- decoder: out = hfin @ Wd + b ----
    hipLaunchKernelGGL((mmT_kernel<128, 0, 0, 0, 768>), dim3(GR, 6, 1), dim3(256), 0, stream,
                       hfin, (const float*)nullptr, (size_t)0,
                       wdh, wdl, dec_b, out, (float*)nullptr);
}

// Round 10
// 201.290 us; speedup vs baseline: 1.7173x; 1.0493x over previous
//
#include <hip/hip_runtime.h>
#include <math.h>

#define N_NODES 10000
#define N_EDGES 160000
#define ET      (N_EDGES + N_NODES)   // with self loops
#define NRG     313                   // ceil(10000/32) row groups
#define AZS     ((size_t)NRG * 4096)  // u16 per K=128 A-pack (313*4*2*64*8)

typedef unsigned short u16;
typedef __attribute__((ext_vector_type(8))) short bf16x8;
typedef __attribute__((ext_vector_type(4))) float f32x4;

__device__ __forceinline__ u16 f2bf(float f) {            // RNE
    union { float f; unsigned u; } v; v.f = f;
    unsigned r = (v.u + 0x7FFFu + ((v.u >> 16) & 1u)) >> 16;
    return (u16)r;
}
__device__ __forceinline__ float bf2f(u16 b) {
    union { unsigned u; float f; } v; v.u = ((unsigned)b) << 16;
    return v.f;
}

// split one fp32 -> trunc hi + RNE lo (identical to splitA8 per-element)
__device__ __forceinline__ void split1(float f, u16& h, u16& l) {
    unsigned u = __float_as_uint(f);
    h = (u16)(u >> 16);
    l = f2bf(f - __uint_as_float(u & 0xffff0000u));
}

// in-register A split: 8 consecutive fp32 -> bf16 hi (trunc) + lo (exact resid)
__device__ __forceinline__ void splitA8(const float* __restrict__ p,
                                        bf16x8& hv, bf16x8& lv) {
    float4 v0 = *reinterpret_cast<const float4*>(p);
    float4 v1 = *reinterpret_cast<const float4*>(p + 4);
    float f[8] = {v0.x, v0.y, v0.z, v0.w, v1.x, v1.y, v1.z, v1.w};
    bf16x8 h, l;
#pragma unroll
    for (int i = 0; i < 8; ++i) {
        unsigned u = __float_as_uint(f[i]);
        h[i] = (short)(u >> 16);
        float r = f[i] - __uint_as_float(u & 0xffff0000u);
        l[i] = (short)(__float_as_uint(r) >> 16);
    }
    hv = h; lv = l;
}

// fragment-pack offset for K=128 A operand: (row, k) -> u16 index
__device__ __forceinline__ size_t packA_off(int row, int k) {
    int rg = row >> 5, fm = (row >> 4) & 1, lr = row & 15;
    int kb = k >> 5, q = (k >> 3) & 3, j = k & 7;
    return ((((size_t)rg * 4 + kb) * 2 + fm) * 64 + q * 16 + lr) * 8 + j;
}

#define MFMA3(A_h, A_l, B_h, B_l, ACC)                                            \
    ACC = __builtin_amdgcn_mfma_f32_16x16x32_bf16(A_h, B_h, ACC, 0, 0, 0);        \
    ACC = __builtin_amdgcn_mfma_f32_16x16x32_bf16(A_h, B_l, ACC, 0, 0, 0);        \
    ACC = __builtin_amdgcn_mfma_f32_16x16x32_bf16(A_l, B_h, ACC, 0, 0, 0);

// async global->LDS, 16 B per lane, wave-uniform LDS base
#define GLD16(SRC, DST)                                                           \
    __builtin_amdgcn_global_load_lds(                                             \
        (const __attribute__((address_space(1))) void*)(SRC),                     \
        (__attribute__((address_space(3))) void*)(DST), 16, 0, 0)

// ---------------------------------------------------------------------------
// Weight pack: fp32 W[K][N] -> MFMA-fragment-ordered bf16 hi/lo.
// ---------------------------------------------------------------------------
__global__ void wpack_all_kernel(const float* __restrict__ W0, u16* p0h, u16* p0l,
                                 const float* __restrict__ W1, u16* p1h, u16* p1l,
                                 const float* __restrict__ W2, u16* p2h, u16* p2l,
                                 const float* __restrict__ W3, u16* p3h, u16* p3l) {
    int idx = blockIdx.x * blockDim.x + threadIdx.x;
    const float* W; u16 *oh, *ol; int K, N, rel;
    if      (idx < 12288) { W = W0; oh = p0h; ol = p0l; K = 768; N = 128; rel = idx; }
    else if (idx < 20480) { W = W1; oh = p1h; ol = p1l; K = 128; N = 512; rel = idx - 12288; }
    else if (idx < 28672) { W = W2; oh = p2h; ol = p2l; K = 512; N = 128; rel = idx - 20480; }
    else if (idx < 40960) { W = W3; oh = p3h; ol = p3l; K = 128; N = 768; rel = idx - 28672; }
    else return;
    int perCg = (K / 32) * 128;
    int cg = rel / perCg, r2 = rel - cg * perCg;
    int kb = r2 >> 7, r3 = r2 & 127;
    int fn = r3 >> 6, lane = r3 & 63;
    int col = cg * 32 + fn * 16 + (lane & 15);
    int k0  = kb * 32 + (lane >> 4) * 8;
    bf16x8 hv, lv;
#pragma unroll
    for (int j = 0; j < 8; ++j) {
        float v = W[(size_t)(k0 + j) * N + col];
        u16 h = f2bf(v);
        hv[j] = (short)h;
        lv[j] = (short)f2bf(v - bf2f(h));
    }
    *(bf16x8*)(oh + (size_t)rel * 8) = hv;
    *(bf16x8*)(ol + (size_t)rel * 8) = lv;
}

// ---------------------------------------------------------------------------
// va1[k][h] = sum_c W1[k, h*128+c] * att_src[h][c]  (and att_dst)
// ---------------------------------------------------------------------------
__global__ void va1_kernel(const float* __restrict__ W1,
                           const float* __restrict__ att_src,
                           const float* __restrict__ att_dst,
                           float* __restrict__ vas, float* __restrict__ vad) {
    int tid = threadIdx.x;
    int k = tid >> 2, h = tid & 3;
    float s = 0.0f, d = 0.0f;
    const float* wr = W1 + (size_t)k * 512 + h * 128;
    const float* as = att_src + h * 128;
    const float* ad = att_dst + h * 128;
    for (int c = 0; c < 128; ++c) {
        float w = wr[c];
        s = fmaf(w, as[c], s);
        d = fmaf(w, ad[c], d);
    }
    vas[k * 4 + h] = s;
    vad[k * 4 + h] = d;
}

// ---------------------------------------------------------------------------
// LDS-pipelined split-bf16 GEMM (packed B), fp32 A — for proj (K=768) and
// gat2 (K=512).
// ---------------------------------------------------------------------------
template<int K, int SRCSEL, int ZC, int ACT, int LDOUT>
__global__ __launch_bounds__(256)
void mmT_kernel(const float* __restrict__ A0, const float* __restrict__ A1,
                size_t azs,
                const u16* __restrict__ Bh, const u16* __restrict__ Bl,
                const float* __restrict__ bias,
                float* __restrict__ out0, float* __restrict__ out1) {
    constexpr int NS = K / 64;
    __shared__ float smem[2 * 2080];           // 2 buffers x 8*260 floats
    const int lane = threadIdx.x & 63;
    const int wid  = threadIdx.x >> 6;
    const int lr = lane & 15, q = lane >> 4;
    const int row0 = blockIdx.x * 32;
    const int z = blockIdx.z;
    const int gcb = blockIdx.y * 128 + z * ZC;

    const float* Ab = SRCSEL ? (z ? A1 : A0) : (A0 + (size_t)z * azs);
    float* outp = (SRCSEL && z) ? out1 : out0;

    const int srow = min(row0 + (lane >> 1), N_NODES - 1);
    const float* sA = Ab + (size_t)srow * K + (lane & 1) * 4;
    float* dg0 = smem + (wid * 2 + 0) * 260;
    float* dg1 = smem + (wid * 2 + 1) * 260;

    const int cg = gcb / 32 + wid;
    const u16* pbh = Bh + (size_t)cg * K * 32 + lane * 8;
    const u16* pbl = Bl + (size_t)cg * K * 32 + lane * 8;

    f32x4 acc[2][2];
#pragma unroll
    for (int i = 0; i < 2; ++i)
#pragma unroll
        for (int j = 0; j < 2; ++j) acc[i][j] = (f32x4){0.f, 0.f, 0.f, 0.f};

    bf16x8 rbh[2][2][2], rbl[2][2][2];         // [bank][fn][ksub]

#define STAGE_T(BUF, S) do {                                                   \
        GLD16(sA + (S) * 64 + (wid * 2 + 0) * 8, dg0 + (BUF) * 2080);          \
        GLD16(sA + (S) * 64 + (wid * 2 + 1) * 8, dg1 + (BUF) * 2080);          \
    } while (0)

    STAGE_T(0, 0);
#pragma unroll
    for (int fn = 0; fn < 2; ++fn)
#pragma unroll
        for (int ks = 0; ks < 2; ++ks) {
            rbh[0][fn][ks] = *(const bf16x8*)(pbh + (ks * 2 + fn) * 512);
            rbl[0][fn][ks] = *(const bf16x8*)(pbl + (ks * 2 + fn) * 512);
        }
    __syncthreads();

#pragma unroll
    for (int s = 0; s < NS; ++s) {
        const int bank = s & 1;
        if (s + 1 < NS) {
            STAGE_T(bank ^ 1, s + 1);
#pragma unroll
            for (int fn = 0; fn < 2; ++fn)
#pragma unroll
                for (int ks = 0; ks < 2; ++ks) {
                    rbh[bank ^ 1][fn][ks] =
                        *(const bf16x8*)(pbh + (((s + 1) * 2 + ks) * 2 + fn) * 512);
                    rbl[bank ^ 1][fn][ks] =
                        *(const bf16x8*)(pbl + (((s + 1) * 2 + ks) * 2 + fn) * 512);
                }
        }
        const float* lb = smem + bank * 2080;
        bf16x8 ah[2][2], al[2][2];
#pragma unroll
        for (int fm = 0; fm < 2; ++fm)
#pragma unroll
            for (int ks = 0; ks < 2; ++ks) {
                const float* fp = lb + (ks * 4 + q) * 260 + (fm * 16 + lr) * 8;
                splitA8(fp, ah[fm][ks], al[fm][ks]);
            }
#pragma unroll
        for (int fm = 0; fm < 2; ++fm)
#pragma unroll
            for (int fn = 0; fn < 2; ++fn)
#pragma unroll
                for (int ks = 0; ks < 2; ++ks) {
                    MFMA3(ah[fm][ks], al[fm][ks],
                          rbh[bank][fn][ks], rbl[bank][fn][ks], acc[fm][fn]);
                }
        __syncthreads();
    }

    int orq = q * 4;
#pragma unroll
    for (int fm = 0; fm < 2; ++fm)
#pragma unroll
        for (int fn = 0; fn < 2; ++fn) {
            int col = gcb + wid * 32 + fn * 16 + lr;
            float bb = bias ? bias[col] : 0.0f;
#pragma unroll
            for (int i = 0; i < 4; ++i) {
                int orow = row0 + fm * 16 + orq + i;
                if (orow < N_NODES) {
                    float r = acc[fm][fn][i] + bb;
                    if (ACT == 1) r = r > 0.0f ? r : expm1f(r);
                    outp[(size_t)orow * LDOUT + col] = r;
                }
            }
        }
#undef STAGE_T
}

// ---------------------------------------------------------------------------
// Barrier-free packed-A / packed-B GEMM, K=128 (mm_head & decoder).
// Every load is a coalesced base+lane*16B chunk; no LDS, no syncthreads.
// Grid (NRG, NT, NH): cols = (y*128 + z*ZC) .. +128; A base += z*azs.
// Garbage rows 10000..10015 only pollute unwritten output rows (row-local).
// ---------------------------------------------------------------------------
template<int ZC, int ACT, int LDOUT>
__global__ __launch_bounds__(256)
void mmP_kernel(const u16* __restrict__ Ah, const u16* __restrict__ Al,
                size_t azs,
                const u16* __restrict__ Bh, const u16* __restrict__ Bl,
                const float* __restrict__ bias,
                float* __restrict__ out) {
    constexpr int K = 128;
    const int lane = threadIdx.x & 63;
    const int wid  = threadIdx.x >> 6;
    const int lr = lane & 15, q = lane >> 4;
    const int rg = blockIdx.x;
    const int row0 = rg * 32;
    const int z = blockIdx.z;
    const int gcb = blockIdx.y * 128 + z * ZC;

    const u16* ah = Ah + (size_t)z * azs + (size_t)rg * 4096 + lane * 8;
    const u16* al = Al + (size_t)z * azs + (size_t)rg * 4096 + lane * 8;
    const int cg = gcb / 32 + wid;
    const u16* bh = Bh + (size_t)cg * K * 32 + lane * 8;
    const u16* bl = Bl + (size_t)cg * K * 32 + lane * 8;

    f32x4 acc[2][2];
#pragma unroll
    for (int i = 0; i < 2; ++i)
#pragma unroll
        for (int j = 0; j < 2; ++j) acc[i][j] = (f32x4){0.f, 0.f, 0.f, 0.f};

#pragma unroll
    for (int kb = 0; kb < 4; ++kb) {
        bf16x8 a0h = *(const bf16x8*)(ah + (kb * 2 + 0) * 512);
        bf16x8 a1h = *(const bf16x8*)(ah + (kb * 2 + 1) * 512);
        bf16x8 a0l = *(const bf16x8*)(al + (kb * 2 + 0) * 512);
        bf16x8 a1l = *(const bf16x8*)(al + (kb * 2 + 1) * 512);
        bf16x8 b0h = *(const bf16x8*)(bh + (kb * 2 + 0) * 512);
        bf16x8 b1h = *(const bf16x8*)(bh + (kb * 2 + 1) * 512);
        bf16x8 b0l = *(const bf16x8*)(bl + (kb * 2 + 0) * 512);
        bf16x8 b1l = *(const bf16x8*)(bl + (kb * 2 + 1) * 512);
        MFMA3(a0h, a0l, b0h, b0l, acc[0][0]);
        MFMA3(a0h, a0l, b1h, b1l, acc[0][1]);
        MFMA3(a1h, a1l, b0h, b0l, acc[1][0]);
        MFMA3(a1h, a1l, b1h, b1l, acc[1][1]);
    }

    int orq = q * 4;
#pragma unroll
    for (int fm = 0; fm < 2; ++fm)
#pragma unroll
        for (int fn = 0; fn < 2; ++fn) {
            int col = gcb + wid * 32 + fn * 16 + lr;
            float bb = bias[col];
#pragma unroll
            for (int i = 0; i < 4; ++i) {
                int orow = row0 + fm * 16 + orq + i;
                if (orow < N_NODES) {
                    float r = acc[fm][fn][i] + bb;
                    if (ACT == 1) r = r > 0.0f ? r : expm1f(r);
                    out[(size_t)orow * LDOUT + col] = r;
                }
            }
        }
}

// ---------------------------------------------------------------------------
// gat1 attention logits from xp
// ---------------------------------------------------------------------------
__global__ void att1_kernel(const float* __restrict__ xp,
                            const float* __restrict__ vas,
                            const float* __restrict__ vad,
                            float* __restrict__ as, float* __restrict__ ad) {
    int wv = threadIdx.x >> 6, lane = threadIdx.x & 63;
    int n = blockIdx.x * 4 + wv;
    float2 v = *reinterpret_cast<const float2*>(xp + (size_t)n * 128 + lane * 2);
    float4 s0 = *reinterpret_cast<const float4*>(vas + (lane * 2) * 4);
    float4 s1 = *reinterpret_cast<const float4*>(vas + (lane * 2 + 1) * 4);
    float4 d0 = *reinterpret_cast<const float4*>(vad + (lane * 2) * 4);
    float4 d1 = *reinterpret_cast<const float4*>(vad + (lane * 2 + 1) * 4);
    float ss[4] = { v.x * s0.x + v.y * s1.x, v.x * s0.y + v.y * s1.y,
                    v.x * s0.z + v.y * s1.z, v.x * s0.w + v.y * s1.w };
    float dd[4] = { v.x * d0.x + v.y * d1.x, v.x * d0.y + v.y * d1.y,
                    v.x * d0.z + v.y * d1.z, v.x * d0.w + v.y * d1.w };
#pragma unroll
    for (int m = 32; m > 0; m >>= 1)
#pragma unroll
        for (int h = 0; h < 4; ++h) {
            ss[h] += __shfl_xor(ss[h], m, 64);
            dd[h] += __shfl_xor(dd[h], m, 64);
        }
    if (lane == 0) {
#pragma unroll
        for (int h = 0; h < 4; ++h) {
            as[(size_t)n * 4 + h] = ss[h];
            ad[(size_t)n * 4 + h] = dd[h];
        }
    }
}

// ---------------------------------------------------------------------------
// gat2 attention logits (H=1)
// ---------------------------------------------------------------------------
__global__ void att2_kernel(const float* __restrict__ h,
                            const float* __restrict__ att_src,
                            const float* __restrict__ att_dst,
                            float* __restrict__ as, float* __restrict__ ad) {
    int wv = threadIdx.x >> 6, lane = threadIdx.x & 63;
    int n = blockIdx.x * 4 + wv;
    const float* hp = h + (size_t)n * 128 + lane * 2;
    float2 v = *reinterpret_cast<const float2*>(hp);
    float2 a = *reinterpret_cast<const float2*>(att_src + lane * 2);
    float2 b = *reinterpret_cast<const float2*>(att_dst + lane * 2);
    float ss = v.x * a.x + v.y * a.y;
    float sd = v.x * b.x + v.y * b.y;
#pragma unroll
    for (int m = 32; m > 0; m >>= 1) {
        ss += __shfl_xor(ss, m, 64);
        sd += __shfl_xor(sd, m, 64);
    }
    if (lane == 0) { as[n] = ss; ad[n] = sd; }
}

// ---------------------------------------------------------------------------
// CSR build (by dst), parallel scan
// ---------------------------------------------------------------------------
__global__ void zero_int_kernel(int* __restrict__ p, int n) {
    int i = blockIdx.x * blockDim.x + threadIdx.x;
    if (i < n) p[i] = 0;
}

__global__ void deg_kernel(const int* __restrict__ ei, int* __restrict__ deg) {
    int e = blockIdx.x * blockDim.x + threadIdx.x;
    if (e >= ET) return;
    int d = (e < N_EDGES) ? ei[N_EDGES + e] : (e - N_EDGES);
    atomicAdd(&deg[d], 1);
}

__global__ void scan1_kernel(const int* __restrict__ deg, int* __restrict__ bsum) {
    __shared__ int sm[256];
    int i = blockIdx.x * 256 + threadIdx.x;
    sm[threadIdx.x] = (i < N_NODES) ? deg[i] : 0;
    __syncthreads();
    for (int s = 128; s > 0; s >>= 1) {
        if (threadIdx.x < s) sm[threadIdx.x] += sm[threadIdx.x + s];
        __syncthreads();
    }
    if (threadIdx.x == 0) bsum[blockIdx.x] = sm[0];
}

__global__ void scan2_kernel(const int* __restrict__ bsum, int* __restrict__ boff,
                             int* __restrict__ off) {
    int lane = threadIdx.x;         // 64 threads, 40 blocks of data
    int v = (lane < 40) ? bsum[lane] : 0;
    int inc = v;
#pragma unroll
    for (int s = 1; s < 64; s <<= 1) {
        int t = __shfl_up(inc, s, 64);
        if (lane >= s) inc += t;
    }
    if (lane < 40) boff[lane] = inc - v;
    if (lane == 63) off[N_NODES] = inc;
}

__global__ void scan3_kernel(const int* __restrict__ deg, const int* __restrict__ boff,
                             int* __restrict__ off, int* __restrict__ cur) {
    __shared__ int sm[256];
    int i = blockIdx.x * 256 + threadIdx.x;
    int v = (i < N_NODES) ? deg[i] : 0;
    sm[threadIdx.x] = v;
    __syncthreads();
    for (int s = 1; s < 256; s <<= 1) {
        int t = (threadIdx.x >= s) ? sm[threadIdx.x - s] : 0;
        __syncthreads();
        sm[threadIdx.x] += t;
        __syncthreads();
    }
    if (i < N_NODES) {
        int ex = boff[blockIdx.x] + sm[threadIdx.x] - v;
        off[i] = ex;
        cur[i] = ex;
    }
}

__global__ void fill_kernel(const int* __restrict__ ei,
                            int* __restrict__ cur, int* __restrict__ csr_src) {
    int e = blockIdx.x * blockDim.x + threadIdx.x;
    if (e >= ET) return;
    int s, d;
    if (e < N_EDGES) { s = ei[e]; d = ei[N_EDGES + e]; }
    else             { s = e - N_EDGES; d = s; }
    int pos = atomicAdd(&cur[d], 1);
    csr_src[pos] = s;
}

// ---------------------------------------------------------------------------
// Segment softmax, wave-per-node
// ---------------------------------------------------------------------------
template<int H>
__global__ void softmax_kernel(const float* __restrict__ as,
                               const float* __restrict__ ad,
                               const int* __restrict__ off,
                               const int* __restrict__ csr_src,
                               float* __restrict__ exw,     // [ET, H]
                               float* __restrict__ inv_s) { // [N, H]
    int wv = threadIdx.x >> 6, lane = threadIdx.x & 63;
    int n = blockIdx.x * 4 + wv;
    int o0 = off[n], o1 = off[n + 1];
    float adn[H], m[H], s[H];
#pragma unroll
    for (int h = 0; h < H; ++h) { adn[h] = ad[(size_t)n * H + h]; m[h] = -1e30f; s[h] = 0.0f; }

    for (int j = o0 + lane; j < o1; j += 64) {
        int sn = csr_src[j];
#pragma unroll
        for (int h = 0; h < H; ++h) {
            float e = as[(size_t)sn * H + h] + adn[h];
            e = e > 0.0f ? e : 0.2f * e;
            m[h] = fmaxf(m[h], e);
        }
    }
#pragma unroll
    for (int mk = 32; mk > 0; mk >>= 1)
#pragma unroll
        for (int h = 0; h < H; ++h) m[h] = fmaxf(m[h], __shfl_xor(m[h], mk, 64));

    for (int j = o0 + lane; j < o1; j += 64) {
        int sn = csr_src[j];
        float exv[H];
#pragma unroll
        for (int h = 0; h < H; ++h) {
            float e = as[(size_t)sn * H + h] + adn[h];
            e = e > 0.0f ? e : 0.2f * e;
            exv[h] = expf(e - m[h]);
            s[h] += exv[h];
        }
        if (H == 4) {
            *reinterpret_cast<float4*>(exw + (size_t)j * 4) =
                make_float4(exv[0], exv[1], exv[2 % H], exv[3 % H]);
        } else {
            exw[j] = exv[0];
        }
    }
#pragma unroll
    for (int mk = 32; mk > 0; mk >>= 1)
#pragma unroll
        for (int h = 0; h < H; ++h) s[h] += __shfl_xor(s[h], mk, 64);

    if (lane == 0) {
#pragma unroll
        for (int h = 0; h < H; ++h) inv_s[(size_t)n * H + h] = 1.0f / (s[h] + 1e-16f);
    }
}

// ---------------------------------------------------------------------------
// gat1 pre-linear aggregation -> fragment-packed bf16 hi/lo per head.
// Block 256 = 2 nodes x 128 channels; all 4 heads per thread.
// ---------------------------------------------------------------------------
__global__ void agg1_kernel(const float* __restrict__ xp,
                            const float* __restrict__ exw,    // [ET][4]
                            const float* __restrict__ inv_s,  // [N][4]
                            const int* __restrict__ off,
                            const int* __restrict__ csr_src,
                            u16* __restrict__ aggPh, u16* __restrict__ aggPl) {
    int sub = threadIdx.x >> 7;
    int c   = threadIdx.x & 127;
    int n   = blockIdx.x * 2 + sub;
    int o0 = off[n], o1 = off[n + 1];

    float a0 = 0.f, a1 = 0.f, a2 = 0.f, a3 = 0.f;
    int j = o0;
    for (; j + 2 <= o1; j += 2) {
        int s0 = csr_src[j], s1 = csr_src[j + 1];
        float4 w0 = *reinterpret_cast<const float4*>(exw + (size_t)j * 4);
        float4 w1 = *reinterpret_cast<const float4*>(exw + (size_t)(j + 1) * 4);
        float v0 = xp[(size_t)s0 * 128 + c];
        float v1 = xp[(size_t)s1 * 128 + c];
        a0 = fmaf(w0.x, v0, a0); a1 = fmaf(w0.y, v0, a1);
        a2 = fmaf(w0.z, v0, a2); a3 = fmaf(w0.w, v0, a3);
        a0 = fmaf(w1.x, v1, a0); a1 = fmaf(w1.y, v1, a1);
        a2 = fmaf(w1.z, v1, a2); a3 = fmaf(w1.w, v1, a3);
    }
    if (j < o1) {
        int s0 = csr_src[j];
        float4 w0 = *reinterpret_cast<const float4*>(exw + (size_t)j * 4);
        float v0 = xp[(size_t)s0 * 128 + c];
        a0 = fmaf(w0.x, v0, a0); a1 = fmaf(w0.y, v0, a1);
        a2 = fmaf(w0.z, v0, a2); a3 = fmaf(w0.w, v0, a3);
    }

    float4 inv = *reinterpret_cast<const float4*>(inv_s + (size_t)n * 4);
    float r[4] = {a0 * inv.x, a1 * inv.y, a2 * inv.z, a3 * inv.w};
    size_t po = packA_off(n, c);
#pragma unroll
    for (int h = 0; h < 4; ++h) {
        u16 hi, lo;
        split1(r[h], hi, lo);
        aggPh[(size_t)h * AZS + po] = hi;
        aggPl[(size_t)h * AZS + po] = lo;
    }
}

// ---------------------------------------------------------------------------
// gat2 weighted gather -> fragment-packed hfin bf16 hi/lo (+bias+beta*gp)
// ---------------------------------------------------------------------------
template<int NPB>
__global__ void gather2_kernel(const float* __restrict__ h,
                               const float* __restrict__ exw,
                               const float* __restrict__ inv_s,
                               const int* __restrict__ off,
                               const int* __restrict__ csr_src,
                               const float* __restrict__ bias,
                               u16* __restrict__ outPh, u16* __restrict__ outPl,
                               const float* __restrict__ gp,
                               const float* __restrict__ beta_p) {
    int sub = threadIdx.x >> 7;
    int c   = threadIdx.x & 127;
    int n   = blockIdx.x * NPB + sub;
    int o0 = off[n], o1 = off[n + 1];

    float acc = 0.0f;
    int j = o0;
    for (; j + 4 <= o1; j += 4) {
        int s0 = csr_src[j + 0], s1 = csr_src[j + 1];
        int s2 = csr_src[j + 2], s3 = csr_src[j + 3];
        float w0 = exw[j + 0], w1 = exw[j + 1];
        float w2 = exw[j + 2], w3 = exw[j + 3];
        float v0 = h[(size_t)s0 * 128 + c];
        float v1 = h[(size_t)s1 * 128 + c];
        float v2 = h[(size_t)s2 * 128 + c];
        float v3 = h[(size_t)s3 * 128 + c];
        acc = fmaf(w0, v0, acc);
        acc = fmaf(w1, v1, acc);
        acc = fmaf(w2, v2, acc);
        acc = fmaf(w3, v3, acc);
    }
    for (; j < o1; ++j) {
        acc = fmaf(exw[j], h[(size_t)csr_src[j] * 128 + c], acc);
    }

    float r = acc * inv_s[n] + bias[c] + beta_p[0] * gp[(size_t)n * 128 + c];
    u16 hi, lo;
    split1(r, hi, lo);
    size_t po = packA_off(n, c);
    outPh[po] = hi;
    outPl[po] = lo;
}

// ---------------------------------------------------------------------------
extern "C" void kernel_launch(void* const* d_in, const int* in_sizes, int n_in,
                              void* d_out, int out_size, void* d_ws, size_t ws_size,
                              hipStream_t stream) {
    const float* x      = (const float*)d_in[0];
    const int*   ei     = (const int*)  d_in[1];
    const float* g      = (const float*)d_in[2];
    const float* proj_W = (const float*)d_in[3];
    const float* proj_b = (const float*)d_in[4];
    const float* gat1_W = (const float*)d_in[5];
    const float* g1_as  = (const float*)d_in[6];
    const float* g1_ad  = (const float*)d_in[7];
    const float* gat1_b = (const float*)d_in[8];
    const float* gat2_W = (const float*)d_in[9];
    const float* g2_as  = (const float*)d_in[10];
    const float* g2_ad  = (const float*)d_in[11];
    const float* gat2_b = (const float*)d_in[12];
    const float* dec_W  = (const float*)d_in[13];
    const float* dec_b  = (const float*)d_in[14];
    const float* beta   = (const float*)d_in[15];
    float* out = (float*)d_out;

    // ---- workspace carve ----
    char* p = (char*)d_ws;
    auto alloc = [&](size_t b) { void* r = (void*)p; p += (b + 255) & ~(size_t)255; return r; };
    float* helu  = (float*)alloc((size_t)10000 * 512 * 4);     // 20.5 MB
    u16*   aggPh = (u16*)alloc(4 * AZS * 2);                   // 10.3 MB
    u16*   aggPl = (u16*)alloc(4 * AZS * 2);                   // 10.3 MB
    u16*   hfPh  = (u16*)alloc(AZS * 2);                       // 2.6 MB
    u16*   hfPl  = (u16*)alloc(AZS * 2);
    float* xp    = (float*)alloc((size_t)10000 * 128 * 4);     // h2 alias
    float* gp    = (float*)alloc((size_t)10000 * 128 * 4);
    u16*   pwh   = (u16*)alloc(768 * 128 * 2);
    u16*   pwl   = (u16*)alloc(768 * 128 * 2);
    u16*   w1h   = (u16*)alloc(128 * 512 * 2);
    u16*   w1l   = (u16*)alloc(128 * 512 * 2);
    u16*   w2h   = (u16*)alloc(512 * 128 * 2);
    u16*   w2l   = (u16*)alloc(512 * 128 * 2);
    u16*   wdh   = (u16*)alloc(128 * 768 * 2);
    u16*   wdl   = (u16*)alloc(128 * 768 * 2);
    float* va1s  = (float*)alloc(128 * 4 * 4);
    float* va1d  = (float*)alloc(128 * 4 * 4);
    float* a1s   = (float*)alloc((size_t)N_NODES * 4 * 4);
    float* a1d   = (float*)alloc((size_t)N_NODES * 4 * 4);
    float* a2s   = (float*)alloc((size_t)N_NODES * 4);
    float* a2d   = (float*)alloc((size_t)N_NODES * 4);
    float* is1   = (float*)alloc((size_t)N_NODES * 4 * 4);
    float* is2   = (float*)alloc((size_t)N_NODES * 4);
    float* exw4  = (float*)alloc((size_t)ET * 4 * 4);
    float* exw1  = (float*)alloc((size_t)ET * 4);
    int*   deg   = (int*)alloc((size_t)N_NODES * 4);
    int*   off   = (int*)alloc((size_t)(N_NODES + 1) * 4);
    int*   cur   = (int*)alloc((size_t)N_NODES * 4);
    int*   csr   = (int*)alloc((size_t)ET * 4);
    int*   bsum  = (int*)alloc(64 * 4);
    int*   boff  = (int*)alloc(64 * 4);
    // aliases (stream-ordered reuse)
    float* h2 = xp;      // after att1/agg1 done with xp

    // ---- weight prep + CSR (parallel scan) ----
    hipLaunchKernelGGL(wpack_all_kernel, dim3(160), dim3(256), 0, stream,
                       proj_W, pwh, pwl, gat1_W, w1h, w1l,
                       gat2_W, w2h, w2l, dec_W, wdh, wdl);
    hipLaunchKernelGGL(va1_kernel, dim3(1), dim3(512), 0, stream,
                       gat1_W, g1_as, g1_ad, va1s, va1d);
    hipLaunchKernelGGL(zero_int_kernel, dim3((N_NODES + 255) / 256), dim3(256), 0, stream, deg, N_NODES);
    hipLaunchKernelGGL(deg_kernel, dim3((ET + 255) / 256), dim3(256), 0, stream, ei, deg);
    hipLaunchKernelGGL(scan1_kernel, dim3(40), dim3(256), 0, stream, deg, bsum);
    hipLaunchKernelGGL(scan2_kernel, dim3(1), dim3(64), 0, stream, bsum, boff, off);
    hipLaunchKernelGGL(scan3_kernel, dim3(40), dim3(256), 0, stream, deg, boff, off, cur);
    hipLaunchKernelGGL(fill_kernel, dim3((ET + 255) / 256), dim3(256), 0, stream, ei, cur, csr);

    // ---- proj: xp = x@Wp+b, gp = g@Wp+b ----
    hipLaunchKernelGGL((mmT_kernel<768, 1, 0, 0, 128>), dim3(NRG, 1, 2), dim3(256), 0, stream,
                       x, g, (size_t)0, pwh, pwl, proj_b, xp, gp);

    // ---- gat1 ----
    hipLaunchKernelGGL(att1_kernel, dim3(N_NODES / 4), dim3(256), 0, stream,
                       xp, va1s, va1d, a1s, a1d);
    hipLaunchKernelGGL(softmax_kernel<4>, dim3(N_NODES / 4), dim3(256), 0, stream,
                       a1s, a1d, off, csr, exw4, is1);
    hipLaunchKernelGGL(agg1_kernel, dim3(N_NODES / 2), dim3(256), 0, stream,
                       xp, exw4, is1, off, csr, aggPh, aggPl);
    // per-head linear + bias + elu -> helu[n, z*128+c]  (packed-A, barrier-free)
    hipLaunchKernelGGL((mmP_kernel<128, 1, 512>), dim3(NRG, 1, 4), dim3(256), 0, stream,
                       aggPh, aggPl, AZS, w1h, w1l, gat1_b, helu);

    // ---- gat2 linear: h2 = helu @ W2 (K=512, LDS-staged) ----
    hipLaunchKernelGGL((mmT_kernel<512, 0, 0, 0, 128>), dim3(NRG, 1, 1), dim3(256), 0, stream,
                       helu, (const float*)nullptr, (size_t)0,
                       w2h, w2l, (const float*)nullptr, h2, (float*)nullptr);
    hipLaunchKernelGGL(att2_kernel, dim3(N_NODES / 4), dim3(256), 0, stream,
                       h2, g2_as, g2_ad, a2s, a2d);
    hipLaunchKernelGGL(softmax_kernel<1>, dim3(N_NODES / 4), dim3(256), 0, stream,
                       a2s, a2d, off, csr, exw1, is2);
    hipLaunchKernelGGL((gather2_kernel<2>), dim3(N_NODES / 2), dim3(256), 0, stream,
                       h2, exw1, is2, off, csr, gat2_b, hfPh, hfPl, gp, beta);

    // ---- decoder: out = hfin @ Wd + b  (packed-A, barrier-free) ----
    hipLaunchKernelGGL((mmP_kernel<0, 0, 768>), dim3(NRG, 6, 1), dim3(256), 0, stream,
                       hfPh, hfPl, (size_t)0, wdh, wdl, dec_b, out);
}

// Round 11
// 178.930 us; speedup vs baseline: 1.9319x; 1.1250x over previous
//
#include <hip/hip_runtime.h>
#include <math.h>

#define N_NODES 10000
#define N_EDGES 160000
#define ET      (N_EDGES + N_NODES)   // with self loops
#define NRG     313                   // ceil(10000/32) row groups
#define AZS     ((size_t)NRG * 4096)  // u16 per K=128 A-pack

typedef unsigned short u16;
typedef __attribute__((ext_vector_type(8))) short bf16x8;
typedef __attribute__((ext_vector_type(4))) float f32x4;

__device__ __forceinline__ u16 f2bf(float f) {            // RNE
    union { float f; unsigned u; } v; v.f = f;
    unsigned r = (v.u + 0x7FFFu + ((v.u >> 16) & 1u)) >> 16;
    return (u16)r;
}
__device__ __forceinline__ float bf2f(u16 b) {
    union { unsigned u; float f; } v; v.u = ((unsigned)b) << 16;
    return v.f;
}

__device__ __forceinline__ void split1(float f, u16& h, u16& l) {
    unsigned u = __float_as_uint(f);
    h = (u16)(u >> 16);
    l = f2bf(f - __uint_as_float(u & 0xffff0000u));
}

__device__ __forceinline__ void splitA8(const float* __restrict__ p,
                                        bf16x8& hv, bf16x8& lv) {
    float4 v0 = *reinterpret_cast<const float4*>(p);
    float4 v1 = *reinterpret_cast<const float4*>(p + 4);
    float f[8] = {v0.x, v0.y, v0.z, v0.w, v1.x, v1.y, v1.z, v1.w};
    bf16x8 h, l;
#pragma unroll
    for (int i = 0; i < 8; ++i) {
        unsigned u = __float_as_uint(f[i]);
        h[i] = (short)(u >> 16);
        float r = f[i] - __uint_as_float(u & 0xffff0000u);
        l[i] = (short)(__float_as_uint(r) >> 16);
    }
    hv = h; lv = l;
}

// fragment-pack offset for K=128 A operand: (row, k) -> u16 index
__device__ __forceinline__ size_t packA_off(int row, int k) {
    int rg = row >> 5, fm = (row >> 4) & 1, lr = row & 15;
    int kb = k >> 5, q = (k >> 3) & 3, j = k & 7;
    return ((((size_t)rg * 4 + kb) * 2 + fm) * 64 + q * 16 + lr) * 8 + j;
}

#define MFMA3(A_h, A_l, B_h, B_l, ACC)                                            \
    ACC = __builtin_amdgcn_mfma_f32_16x16x32_bf16(A_h, B_h, ACC, 0, 0, 0);        \
    ACC = __builtin_amdgcn_mfma_f32_16x16x32_bf16(A_h, B_l, ACC, 0, 0, 0);        \
    ACC = __builtin_amdgcn_mfma_f32_16x16x32_bf16(A_l, B_h, ACC, 0, 0, 0);

#define GLD16(SRC, DST)                                                           \
    __builtin_amdgcn_global_load_lds(                                             \
        (const __attribute__((address_space(1))) void*)(SRC),                     \
        (__attribute__((address_space(3))) void*)(DST), 16, 0, 0)

// ---------------------------------------------------------------------------
// Fused prep: blocks 0..159 wpack all 4 weights; block 160 va1; 161..200 zero deg.
// ---------------------------------------------------------------------------
__global__ void prep_kernel(const float* __restrict__ W0, u16* p0h, u16* p0l,
                            const float* __restrict__ W1, u16* p1h, u16* p1l,
                            const float* __restrict__ W2, u16* p2h, u16* p2l,
                            const float* __restrict__ W3, u16* p3h, u16* p3l,
                            const float* __restrict__ att_src,
                            const float* __restrict__ att_dst,
                            float* __restrict__ vas, float* __restrict__ vad,
                            int* __restrict__ deg) {
    int b = blockIdx.x, tid = threadIdx.x;
    if (b < 160) {
        int idx = b * 256 + tid;
        const float* W; u16 *oh, *ol; int K, N, rel;
        if      (idx < 12288) { W = W0; oh = p0h; ol = p0l; K = 768; N = 128; rel = idx; }
        else if (idx < 20480) { W = W1; oh = p1h; ol = p1l; K = 128; N = 512; rel = idx - 12288; }
        else if (idx < 28672) { W = W2; oh = p2h; ol = p2l; K = 512; N = 128; rel = idx - 20480; }
        else                  { W = W3; oh = p3h; ol = p3l; K = 128; N = 768; rel = idx - 28672; }
        int perCg = (K / 32) * 128;
        int cg = rel / perCg, r2 = rel - cg * perCg;
        int kb = r2 >> 7, r3 = r2 & 127;
        int fn = r3 >> 6, lane = r3 & 63;
        int col = cg * 32 + fn * 16 + (lane & 15);
        int k0  = kb * 32 + (lane >> 4) * 8;
        bf16x8 hv, lv;
#pragma unroll
        for (int j = 0; j < 8; ++j) {
            float v = W[(size_t)(k0 + j) * N + col];
            u16 h = f2bf(v);
            hv[j] = (short)h;
            lv[j] = (short)f2bf(v - bf2f(h));
        }
        *(bf16x8*)(oh + (size_t)rel * 8) = hv;
        *(bf16x8*)(ol + (size_t)rel * 8) = lv;
    } else if (b == 160) {
        for (int it = tid; it < 512; it += 256) {
            int k = it >> 2, h = it & 3;
            float s = 0.0f, d = 0.0f;
            const float* wr = W1 + (size_t)k * 512 + h * 128;
            const float* as = att_src + h * 128;
            const float* ad = att_dst + h * 128;
            for (int c = 0; c < 128; ++c) {
                float w = wr[c];
                s = fmaf(w, as[c], s);
                d = fmaf(w, ad[c], d);
            }
            vas[k * 4 + h] = s;
            vad[k * 4 + h] = d;
        }
    } else {
        int i = (b - 161) * 256 + tid;
        if (i < N_NODES) deg[i] = 0;
    }
}

// ---------------------------------------------------------------------------
// LDS-pipelined split-bf16 GEMM (packed B), fp32 A — proj (K=768), gat2 (K=512)
// ---------------------------------------------------------------------------
template<int K, int SRCSEL, int ZC, int ACT, int LDOUT>
__global__ __launch_bounds__(256)
void mmT_kernel(const float* __restrict__ A0, const float* __restrict__ A1,
                size_t azs,
                const u16* __restrict__ Bh, const u16* __restrict__ Bl,
                const float* __restrict__ bias,
                float* __restrict__ out0, float* __restrict__ out1) {
    constexpr int NS = K / 64;
    __shared__ float smem[2 * 2080];
    const int lane = threadIdx.x & 63;
    const int wid  = threadIdx.x >> 6;
    const int lr = lane & 15, q = lane >> 4;
    const int row0 = blockIdx.x * 32;
    const int z = blockIdx.z;
    const int gcb = blockIdx.y * 128 + z * ZC;

    const float* Ab = SRCSEL ? (z ? A1 : A0) : (A0 + (size_t)z * azs);
    float* outp = (SRCSEL && z) ? out1 : out0;

    const int srow = min(row0 + (lane >> 1), N_NODES - 1);
    const float* sA = Ab + (size_t)srow * K + (lane & 1) * 4;
    float* dg0 = smem + (wid * 2 + 0) * 260;
    float* dg1 = smem + (wid * 2 + 1) * 260;

    const int cg = gcb / 32 + wid;
    const u16* pbh = Bh + (size_t)cg * K * 32 + lane * 8;
    const u16* pbl = Bl + (size_t)cg * K * 32 + lane * 8;

    f32x4 acc[2][2];
#pragma unroll
    for (int i = 0; i < 2; ++i)
#pragma unroll
        for (int j = 0; j < 2; ++j) acc[i][j] = (f32x4){0.f, 0.f, 0.f, 0.f};

    bf16x8 rbh[2][2][2], rbl[2][2][2];

#define STAGE_T(BUF, S) do {                                                   \
        GLD16(sA + (S) * 64 + (wid * 2 + 0) * 8, dg0 + (BUF) * 2080);          \
        GLD16(sA + (S) * 64 + (wid * 2 + 1) * 8, dg1 + (BUF) * 2080);          \
    } while (0)

    STAGE_T(0, 0);
#pragma unroll
    for (int fn = 0; fn < 2; ++fn)
#pragma unroll
        for (int ks = 0; ks < 2; ++ks) {
            rbh[0][fn][ks] = *(const bf16x8*)(pbh + (ks * 2 + fn) * 512);
            rbl[0][fn][ks] = *(const bf16x8*)(pbl + (ks * 2 + fn) * 512);
        }
    __syncthreads();

#pragma unroll
    for (int s = 0; s < NS; ++s) {
        const int bank = s & 1;
        if (s + 1 < NS) {
            STAGE_T(bank ^ 1, s + 1);
#pragma unroll
            for (int fn = 0; fn < 2; ++fn)
#pragma unroll
                for (int ks = 0; ks < 2; ++ks) {
                    rbh[bank ^ 1][fn][ks] =
                        *(const bf16x8*)(pbh + (((s + 1) * 2 + ks) * 2 + fn) * 512);
                    rbl[bank ^ 1][fn][ks] =
                        *(const bf16x8*)(pbl + (((s + 1) * 2 + ks) * 2 + fn) * 512);
                }
        }
        const float* lb = smem + bank * 2080;
        bf16x8 ah[2][2], al[2][2];
#pragma unroll
        for (int fm = 0; fm < 2; ++fm)
#pragma unroll
            for (int ks = 0; ks < 2; ++ks) {
                const float* fp = lb + (ks * 4 + q) * 260 + (fm * 16 + lr) * 8;
                splitA8(fp, ah[fm][ks], al[fm][ks]);
            }
#pragma unroll
        for (int fm = 0; fm < 2; ++fm)
#pragma unroll
            for (int fn = 0; fn < 2; ++fn)
#pragma unroll
                for (int ks = 0; ks < 2; ++ks) {
                    MFMA3(ah[fm][ks], al[fm][ks],
                          rbh[bank][fn][ks], rbl[bank][fn][ks], acc[fm][fn]);
                }
        __syncthreads();
    }

    int orq = q * 4;
#pragma unroll
    for (int fm = 0; fm < 2; ++fm)
#pragma unroll
        for (int fn = 0; fn < 2; ++fn) {
            int col = gcb + wid * 32 + fn * 16 + lr;
            float bb = bias ? bias[col] : 0.0f;
#pragma unroll
            for (int i = 0; i < 4; ++i) {
                int orow = row0 + fm * 16 + orq + i;
                if (orow < N_NODES) {
                    float r = acc[fm][fn][i] + bb;
                    if (ACT == 1) r = r > 0.0f ? r : expm1f(r);
                    outp[(size_t)orow * LDOUT + col] = r;
                }
            }
        }
#undef STAGE_T
}

// ---------------------------------------------------------------------------
// Barrier-free packed-A / packed-B GEMM, K=128 (mm_head & decoder).
// ---------------------------------------------------------------------------
template<int ZC, int ACT, int LDOUT>
__global__ __launch_bounds__(256)
void mmP_kernel(const u16* __restrict__ Ah, const u16* __restrict__ Al,
                size_t azs,
                const u16* __restrict__ Bh, const u16* __restrict__ Bl,
                const float* __restrict__ bias,
                float* __restrict__ out) {
    constexpr int K = 128;
    const int lane = threadIdx.x & 63;
    const int wid  = threadIdx.x >> 6;
    const int lr = lane & 15, q = lane >> 4;
    const int rg = blockIdx.x;
    const int row0 = rg * 32;
    const int z = blockIdx.z;
    const int gcb = blockIdx.y * 128 + z * ZC;

    const u16* ah = Ah + (size_t)z * azs + (size_t)rg * 4096 + lane * 8;
    const u16* al = Al + (size_t)z * azs + (size_t)rg * 4096 + lane * 8;
    const int cg = gcb / 32 + wid;
    const u16* bh = Bh + (size_t)cg * K * 32 + lane * 8;
    const u16* bl = Bl + (size_t)cg * K * 32 + lane * 8;

    f32x4 acc[2][2];
#pragma unroll
    for (int i = 0; i < 2; ++i)
#pragma unroll
        for (int j = 0; j < 2; ++j) acc[i][j] = (f32x4){0.f, 0.f, 0.f, 0.f};

#pragma unroll
    for (int kb = 0; kb < 4; ++kb) {
        bf16x8 a0h = *(const bf16x8*)(ah + (kb * 2 + 0) * 512);
        bf16x8 a1h = *(const bf16x8*)(ah + (kb * 2 + 1) * 512);
        bf16x8 a0l = *(const bf16x8*)(al + (kb * 2 + 0) * 512);
        bf16x8 a1l = *(const bf16x8*)(al + (kb * 2 + 1) * 512);
        bf16x8 b0h = *(const bf16x8*)(bh + (kb * 2 + 0) * 512);
        bf16x8 b1h = *(const bf16x8*)(bh + (kb * 2 + 1) * 512);
        bf16x8 b0l = *(const bf16x8*)(bl + (kb * 2 + 0) * 512);
        bf16x8 b1l = *(const bf16x8*)(bl + (kb * 2 + 1) * 512);
        MFMA3(a0h, a0l, b0h, b0l, acc[0][0]);
        MFMA3(a0h, a0l, b1h, b1l, acc[0][1]);
        MFMA3(a1h, a1l, b0h, b0l, acc[1][0]);
        MFMA3(a1h, a1l, b1h, b1l, acc[1][1]);
    }

    int orq = q * 4;
#pragma unroll
    for (int fm = 0; fm < 2; ++fm)
#pragma unroll
        for (int fn = 0; fn < 2; ++fn) {
            int col = gcb + wid * 32 + fn * 16 + lr;
            float bb = bias[col];
#pragma unroll
            for (int i = 0; i < 4; ++i) {
                int orow = row0 + fm * 16 + orq + i;
                if (orow < N_NODES) {
                    float r = acc[fm][fn][i] + bb;
                    if (ACT == 1) r = r > 0.0f ? r : expm1f(r);
                    out[(size_t)orow * LDOUT + col] = r;
                }
            }
        }
}

// ---------------------------------------------------------------------------
// att logits
// ---------------------------------------------------------------------------
__global__ void att1_kernel(const float* __restrict__ xp,
                            const float* __restrict__ vas,
                            const float* __restrict__ vad,
                            float* __restrict__ as, float* __restrict__ ad) {
    int wv = threadIdx.x >> 6, lane = threadIdx.x & 63;
    int n = blockIdx.x * 4 + wv;
    float2 v = *reinterpret_cast<const float2*>(xp + (size_t)n * 128 + lane * 2);
    float4 s0 = *reinterpret_cast<const float4*>(vas + (lane * 2) * 4);
    float4 s1 = *reinterpret_cast<const float4*>(vas + (lane * 2 + 1) * 4);
    float4 d0 = *reinterpret_cast<const float4*>(vad + (lane * 2) * 4);
    float4 d1 = *reinterpret_cast<const float4*>(vad + (lane * 2 + 1) * 4);
    float ss[4] = { v.x * s0.x + v.y * s1.x, v.x * s0.y + v.y * s1.y,
                    v.x * s0.z + v.y * s1.z, v.x * s0.w + v.y * s1.w };
    float dd[4] = { v.x * d0.x + v.y * d1.x, v.x * d0.y + v.y * d1.y,
                    v.x * d0.z + v.y * d1.z, v.x * d0.w + v.y * d1.w };
#pragma unroll
    for (int m = 32; m > 0; m >>= 1)
#pragma unroll
        for (int h = 0; h < 4; ++h) {
            ss[h] += __shfl_xor(ss[h], m, 64);
            dd[h] += __shfl_xor(dd[h], m, 64);
        }
    if (lane == 0) {
#pragma unroll
        for (int h = 0; h < 4; ++h) {
            as[(size_t)n * 4 + h] = ss[h];
            ad[(size_t)n * 4 + h] = dd[h];
        }
    }
}

__global__ void att2_kernel(const float* __restrict__ h,
                            const float* __restrict__ att_src,
                            const float* __restrict__ att_dst,
                            float* __restrict__ as, float* __restrict__ ad) {
    int wv = threadIdx.x >> 6, lane = threadIdx.x & 63;
    int n = blockIdx.x * 4 + wv;
    const float* hp = h + (size_t)n * 128 + lane * 2;
    float2 v = *reinterpret_cast<const float2*>(hp);
    float2 a = *reinterpret_cast<const float2*>(att_src + lane * 2);
    float2 b = *reinterpret_cast<const float2*>(att_dst + lane * 2);
    float ss = v.x * a.x + v.y * a.y;
    float sd = v.x * b.x + v.y * b.y;
#pragma unroll
    for (int m = 32; m > 0; m >>= 1) {
        ss += __shfl_xor(ss, m, 64);
        sd += __shfl_xor(sd, m, 64);
    }
    if (lane == 0) { as[n] = ss; ad[n] = sd; }
}

// ---------------------------------------------------------------------------
// CSR build
// ---------------------------------------------------------------------------
__global__ void deg_kernel(const int* __restrict__ ei, int* __restrict__ deg) {
    int e = blockIdx.x * blockDim.x + threadIdx.x;
    if (e >= ET) return;
    int d = (e < N_EDGES) ? ei[N_EDGES + e] : (e - N_EDGES);
    atomicAdd(&deg[d], 1);
}

__global__ void scan1_kernel(const int* __restrict__ deg, int* __restrict__ bsum) {
    __shared__ int sm[256];
    int i = blockIdx.x * 256 + threadIdx.x;
    sm[threadIdx.x] = (i < N_NODES) ? deg[i] : 0;
    __syncthreads();
    for (int s = 128; s > 0; s >>= 1) {
        if (threadIdx.x < s) sm[threadIdx.x] += sm[threadIdx.x + s];
        __syncthreads();
    }
    if (threadIdx.x == 0) bsum[blockIdx.x] = sm[0];
}

__global__ void scan3_kernel(const int* __restrict__ deg, const int* __restrict__ bsum,
                             int* __restrict__ off, int* __restrict__ cur) {
    __shared__ int sm[256];
    __shared__ int sb[40];
    __shared__ int bofs;
    int tid = threadIdx.x;
    if (tid < 40) sb[tid] = bsum[tid];
    int i = blockIdx.x * 256 + tid;
    int v = (i < N_NODES) ? deg[i] : 0;
    sm[tid] = v;
    __syncthreads();
    if (tid == 0) {
        int s = 0;
        for (int b = 0; b < blockIdx.x; ++b) s += sb[b];
        bofs = s;
    }
    for (int s = 1; s < 256; s <<= 1) {
        int t = (tid >= s) ? sm[tid - s] : 0;
        __syncthreads();
        sm[tid] += t;
        __syncthreads();
    }
    if (i < N_NODES) {
        int ex = bofs + sm[tid] - v;
        off[i] = ex;
        cur[i] = ex;
    }
    if (blockIdx.x == 0 && tid == 0) off[N_NODES] = ET;
}

__global__ void fill_kernel(const int* __restrict__ ei,
                            int* __restrict__ cur, int* __restrict__ csr_src) {
    int e = blockIdx.x * blockDim.x + threadIdx.x;
    if (e >= ET) return;
    int s, d;
    if (e < N_EDGES) { s = ei[e]; d = ei[N_EDGES + e]; }
    else             { s = e - N_EDGES; d = s; }
    int pos = atomicAdd(&cur[d], 1);
    csr_src[pos] = s;
}

// ---------------------------------------------------------------------------
// Fused softmax + aggregation, layer 1 (H=4). Block 128 thr = 1 node.
// Phase 1: m/s per head (2-wave shfl+LDS reduce). Phase 2: chunked LDS
// weights, channel-threads aggregate; write fragment-packed bf16 hi/lo.
// ---------------------------------------------------------------------------
__global__ __launch_bounds__(128)
void smagg1_kernel(const float* __restrict__ xp,
                   const float* __restrict__ a1s, const float* __restrict__ a1d,
                   const int* __restrict__ off, const int* __restrict__ csr,
                   u16* __restrict__ aggPh, u16* __restrict__ aggPl) {
    int n = blockIdx.x;
    int tid = threadIdx.x, lane = tid & 63, wv = tid >> 6;
    int o0 = off[n], o1 = off[n + 1];
    __shared__ float red[2][8];
    __shared__ float wsh[128][4];
    __shared__ int   ssh[128];

    float4 adv = *reinterpret_cast<const float4*>(a1d + (size_t)n * 4);
    float adn[4] = {adv.x, adv.y, adv.z, adv.w};

    float m[4] = {-1e30f, -1e30f, -1e30f, -1e30f};
    for (int j = o0 + tid; j < o1; j += 128) {
        int sn = csr[j];
        float4 asv = *reinterpret_cast<const float4*>(a1s + (size_t)sn * 4);
        float e0 = asv.x + adn[0]; e0 = e0 > 0.f ? e0 : 0.2f * e0; m[0] = fmaxf(m[0], e0);
        float e1 = asv.y + adn[1]; e1 = e1 > 0.f ? e1 : 0.2f * e1; m[1] = fmaxf(m[1], e1);
        float e2 = asv.z + adn[2]; e2 = e2 > 0.f ? e2 : 0.2f * e2; m[2] = fmaxf(m[2], e2);
        float e3 = asv.w + adn[3]; e3 = e3 > 0.f ? e3 : 0.2f * e3; m[3] = fmaxf(m[3], e3);
    }
#pragma unroll
    for (int mk = 32; mk > 0; mk >>= 1)
#pragma unroll
        for (int h = 0; h < 4; ++h) m[h] = fmaxf(m[h], __shfl_xor(m[h], mk, 64));
    if (lane == 0)
#pragma unroll
        for (int h = 0; h < 4; ++h) red[wv][h] = m[h];
    __syncthreads();
#pragma unroll
    for (int h = 0; h < 4; ++h) m[h] = fmaxf(red[0][h], red[1][h]);

    float s4[4] = {0.f, 0.f, 0.f, 0.f};
    for (int j = o0 + tid; j < o1; j += 128) {
        int sn = csr[j];
        float4 asv = *reinterpret_cast<const float4*>(a1s + (size_t)sn * 4);
        float e0 = asv.x + adn[0]; e0 = e0 > 0.f ? e0 : 0.2f * e0; s4[0] += expf(e0 - m[0]);
        float e1 = asv.y + adn[1]; e1 = e1 > 0.f ? e1 : 0.2f * e1; s4[1] += expf(e1 - m[1]);
        float e2 = asv.z + adn[2]; e2 = e2 > 0.f ? e2 : 0.2f * e2; s4[2] += expf(e2 - m[2]);
        float e3 = asv.w + adn[3]; e3 = e3 > 0.f ? e3 : 0.2f * e3; s4[3] += expf(e3 - m[3]);
    }
#pragma unroll
    for (int mk = 32; mk > 0; mk >>= 1)
#pragma unroll
        for (int h = 0; h < 4; ++h) s4[h] += __shfl_xor(s4[h], mk, 64);
    if (lane == 0)
#pragma unroll
        for (int h = 0; h < 4; ++h) red[wv][4 + h] = s4[h];
    __syncthreads();
    float inv[4];
#pragma unroll
    for (int h = 0; h < 4; ++h) inv[h] = 1.0f / (red[0][4 + h] + red[1][4 + h] + 1e-16f);

    float a0 = 0.f, a1 = 0.f, a2 = 0.f, a3 = 0.f;
    for (int base = o0; base < o1; base += 128) {
        __syncthreads();
        int j = base + tid;
        if (j < o1) {
            int sn = csr[j];
            ssh[tid] = sn;
            float4 asv = *reinterpret_cast<const float4*>(a1s + (size_t)sn * 4);
            float e0 = asv.x + adn[0]; e0 = e0 > 0.f ? e0 : 0.2f * e0; wsh[tid][0] = expf(e0 - m[0]);
            float e1 = asv.y + adn[1]; e1 = e1 > 0.f ? e1 : 0.2f * e1; wsh[tid][1] = expf(e1 - m[1]);
            float e2 = asv.z + adn[2]; e2 = e2 > 0.f ? e2 : 0.2f * e2; wsh[tid][2] = expf(e2 - m[2]);
            float e3 = asv.w + adn[3]; e3 = e3 > 0.f ? e3 : 0.2f * e3; wsh[tid][3] = expf(e3 - m[3]);
        }
        __syncthreads();
        int cnt = min(128, o1 - base);
        for (int e2i = 0; e2i < cnt; ++e2i) {
            float v = xp[(size_t)ssh[e2i] * 128 + tid];
            float4 w = *reinterpret_cast<const float4*>(&wsh[e2i][0]);
            a0 = fmaf(w.x, v, a0); a1 = fmaf(w.y, v, a1);
            a2 = fmaf(w.z, v, a2); a3 = fmaf(w.w, v, a3);
        }
    }

    float r[4] = {a0 * inv[0], a1 * inv[1], a2 * inv[2], a3 * inv[3]};
    size_t po = packA_off(n, tid);
#pragma unroll
    for (int h = 0; h < 4; ++h) {
        u16 hi, lo;
        split1(r[h], hi, lo);
        aggPh[(size_t)h * AZS + po] = hi;
        aggPl[(size_t)h * AZS + po] = lo;
    }
}

// ---------------------------------------------------------------------------
// Fused softmax + gather, layer 2 (H=1) + bias + beta*gp. Block 128 = 1 node.
// ---------------------------------------------------------------------------
__global__ __launch_bounds__(128)
void smgather2_kernel(const float* __restrict__ h2,
                      const float* __restrict__ a2s, const float* __restrict__ a2d,
                      const int* __restrict__ off, const int* __restrict__ csr,
                      const float* __restrict__ bias,
                      u16* __restrict__ outPh, u16* __restrict__ outPl,
                      const float* __restrict__ gp,
                      const float* __restrict__ beta_p) {
    int n = blockIdx.x;
    int tid = threadIdx.x, lane = tid & 63, wv = tid >> 6;
    int o0 = off[n], o1 = off[n + 1];
    __shared__ float red[2][2];
    __shared__ float wsh[128];
    __shared__ int   ssh[128];

    float adn = a2d[n];
    float m = -1e30f;
    for (int j = o0 + tid; j < o1; j += 128) {
        float e = a2s[csr[j]] + adn;
        e = e > 0.f ? e : 0.2f * e;
        m = fmaxf(m, e);
    }
#pragma unroll
    for (int mk = 32; mk > 0; mk >>= 1) m = fmaxf(m, __shfl_xor(m, mk, 64));
    if (lane == 0) red[wv][0] = m;
    __syncthreads();
    m = fmaxf(red[0][0], red[1][0]);

    float s = 0.f;
    for (int j = o0 + tid; j < o1; j += 128) {
        float e = a2s[csr[j]] + adn;
        e = e > 0.f ? e : 0.2f * e;
        s += expf(e - m);
    }
#pragma unroll
    for (int mk = 32; mk > 0; mk >>= 1) s += __shfl_xor(s, mk, 64);
    if (lane == 0) red[wv][1] = s;
    __syncthreads();
    float inv = 1.0f / (red[0][1] + red[1][1] + 1e-16f);

    float acc = 0.f;
    for (int base = o0; base < o1; base += 128) {
        __syncthreads();
        int j = base + tid;
        if (j < o1) {
            int sn = csr[j];
            ssh[tid] = sn;
            float e = a2s[sn] + adn;
            e = e > 0.f ? e : 0.2f * e;
            wsh[tid] = expf(e - m);
        }
        __syncthreads();
        int cnt = min(128, o1 - base);
        for (int e2i = 0; e2i < cnt; ++e2i) {
            acc = fmaf(wsh[e2i], h2[(size_t)ssh[e2i] * 128 + tid], acc);
        }
    }

    float r = acc * inv + bias[tid] + beta_p[0] * gp[(size_t)n * 128 + tid];
    u16 hi, lo;
    split1(r, hi, lo);
    size_t po = packA_off(n, tid);
    outPh[po] = hi;
    outPl[po] = lo;
}

// ---------------------------------------------------------------------------
extern "C" void kernel_launch(void* const* d_in, const int* in_sizes, int n_in,
                              void* d_out, int out_size, void* d_ws, size_t ws_size,
                              hipStream_t stream) {
    const float* x      = (const float*)d_in[0];
    const int*   ei     = (const int*)  d_in[1];
    const float* g      = (const float*)d_in[2];
    const float* proj_W = (const float*)d_in[3];
    const float* proj_b = (const float*)d_in[4];
    const float* gat1_W = (const float*)d_in[5];
    const float* g1_as  = (const float*)d_in[6];
    const float* g1_ad  = (const float*)d_in[7];
    const float* gat1_b = (const float*)d_in[8];
    const float* gat2_W = (const float*)d_in[9];
    const float* g2_as  = (const float*)d_in[10];
    const float* g2_ad  = (const float*)d_in[11];
    const float* gat2_b = (const float*)d_in[12];
    const float* dec_W  = (const float*)d_in[13];
    const float* dec_b  = (const float*)d_in[14];
    const float* beta   = (const float*)d_in[15];
    float* out = (float*)d_out;

    // ---- workspace carve ----
    char* p = (char*)d_ws;
    auto alloc = [&](size_t b) { void* r = (void*)p; p += (b + 255) & ~(size_t)255; return r; };
    float* helu  = (float*)alloc((size_t)10000 * 512 * 4);
    u16*   aggPh = (u16*)alloc(4 * AZS * 2);
    u16*   aggPl = (u16*)alloc(4 * AZS * 2);
    u16*   hfPh  = (u16*)alloc(AZS * 2);
    u16*   hfPl  = (u16*)alloc(AZS * 2);
    float* xp    = (float*)alloc((size_t)10000 * 128 * 4);     // h2 alias
    float* gp    = (float*)alloc((size_t)10000 * 128 * 4);
    u16*   pwh   = (u16*)alloc(768 * 128 * 2);
    u16*   pwl   = (u16*)alloc(768 * 128 * 2);
    u16*   w1h   = (u16*)alloc(128 * 512 * 2);
    u16*   w1l   = (u16*)alloc(128 * 512 * 2);
    u16*   w2h   = (u16*)alloc(512 * 128 * 2);
    u16*   w2l   = (u16*)alloc(512 * 128 * 2);
    u16*   wdh   = (u16*)alloc(128 * 768 * 2);
    u16*   wdl   = (u16*)alloc(128 * 768 * 2);
    float* va1s  = (float*)alloc(128 * 4 * 4);
    float* va1d  = (float*)alloc(128 * 4 * 4);
    float* a1s   = (float*)alloc((size_t)N_NODES * 4 * 4);
    float* a1d   = (float*)alloc((size_t)N_NODES * 4 * 4);
    float* a2s   = (float*)alloc((size_t)N_NODES * 4);
    float* a2d   = (float*)alloc((size_t)N_NODES * 4);
    int*   deg   = (int*)alloc((size_t)N_NODES * 4);
    int*   off   = (int*)alloc((size_t)(N_NODES + 1) * 4);
    int*   cur   = (int*)alloc((size_t)N_NODES * 4);
    int*   csr   = (int*)alloc((size_t)ET * 4);
    int*   bsum  = (int*)alloc(64 * 4);
    // aliases
    float* h2 = xp;

    // ---- fused prep (wpack + va1 + deg zero) ----
    hipLaunchKernelGGL(prep_kernel, dim3(201), dim3(256), 0, stream,
                       proj_W, pwh, pwl, gat1_W, w1h, w1l,
                       gat2_W, w2h, w2l, dec_W, wdh, wdl,
                       g1_as, g1_ad, va1s, va1d, deg);
    hipLaunchKernelGGL(deg_kernel, dim3((ET + 255) / 256), dim3(256), 0, stream, ei, deg);
    hipLaunchKernelGGL(scan1_kernel, dim3(40), dim3(256), 0, stream, deg, bsum);
    hipLaunchKernelGGL(scan3_kernel, dim3(40), dim3(256), 0, stream, deg, bsum, off, cur);
    hipLaunchKernelGGL(fill_kernel, dim3((ET + 255) / 256), dim3(256), 0, stream, ei, cur, csr);

    // ---- proj: xp = x@Wp+b, gp = g@Wp+b ----
    hipLaunchKernelGGL((mmT_kernel<768, 1, 0, 0, 128>), dim3(NRG, 1, 2), dim3(256), 0, stream,
                       x, g, (size_t)0, pwh, pwl, proj_b, xp, gp);

    // ---- gat1 ----
    hipLaunchKernelGGL(att1_kernel, dim3(N_NODES / 4), dim3(256), 0, stream,
                       xp, va1s, va1d, a1s, a1d);
    hipLaunchKernelGGL(smagg1_kernel, dim3(N_NODES), dim3(128), 0, stream,
                       xp, a1s, a1d, off, csr, aggPh, aggPl);
    hipLaunchKernelGGL((mmP_kernel<128, 1, 512>), dim3(NRG, 1, 4), dim3(256), 0, stream,
                       aggPh, aggPl, AZS, w1h, w1l, gat1_b, helu);

    // ---- gat2 ----
    hipLaunchKernelGGL((mmT_kernel<512, 0, 0, 0, 128>), dim3(NRG, 1, 1), dim3(256), 0, stream,
                       helu, (const float*)nullptr, (size_t)0,
                       w2h, w2l, (const float*)nullptr, h2, (float*)nullptr);
    hipLaunchKernelGGL(att2_kernel, dim3(N_NODES / 4), dim3(256), 0, stream,
                       h2, g2_as, g2_ad, a2s, a2d);
    hipLaunchKernelGGL(smgather2_kernel, dim3(N_NODES), dim3(128), 0, stream,
                       h2, a2s, a2d, off, csr, gat2_b, hfPh, hfPl, gp, beta);

    // ---- decoder ----
    hipLaunchKernelGGL((mmP_kernel<0, 0, 768>), dim3(NRG, 6, 1), dim3(256), 0, stream,
                       hfPh, hfPl, (size_t)0, wdh, wdl, dec_b, out);
}